// Round 14
// baseline (322.446 us; speedup 1.0000x reference)
//
#include <hip/hip_runtime.h>

#define NN 40000
#define DDIM 64
#define KE 16
#define EE 640000
#define BNEPS 1e-5f

// Finalize BN coefficients from raw sums: stats layout [sum[C], sumsq[C]].
__device__ __forceinline__ void bn_coeff(const float* __restrict__ S, int C, int c,
                                         const float* __restrict__ g, const float* __restrict__ b,
                                         float inv_n, float& sc, float& sh)
{
    float m   = S[c] * inv_n;
    float var = S[C + c] * inv_n - m * m;
    float r   = rsqrtf(var + BNEPS);
    sc = g[c] * r;
    sh = b[c] - m * sc;
}

// out[r][c] = sum_d f(in[r][d]) * W[d][c], 64x64 W, optional BN+ReLU input transform,
// optional raw column-stats accumulation on the output.
template<int TRN>
__global__ __launch_bounds__(256) void gemm64_k(
    const float* __restrict__ in,
    const float* __restrict__ W0, const float* __restrict__ W1, const float* __restrict__ W2,
    float* __restrict__ out0, float* __restrict__ out1, float* __restrict__ out2,
    const float* __restrict__ Sin, const float* __restrict__ gamma, const float* __restrict__ beta,
    float inv_n, float* __restrict__ Sout)
{
    const float* W = (blockIdx.y == 0) ? W0 : ((blockIdx.y == 1) ? W1 : W2);
    float* out     = (blockIdx.y == 0) ? out0 : ((blockIdx.y == 1) ? out1 : out2);

    __shared__ float Wl[64][64];
    __shared__ float inl[64][65];
    __shared__ float scl[64], shl[64];
    __shared__ float ssum[64], ssq[64];

    const int t = threadIdx.x;
    if (t < 64) {
        if (TRN) { float sc, sh; bn_coeff(Sin, 64, t, gamma, beta, inv_n, sc, sh); scl[t] = sc; shl[t] = sh; }
        ssum[t] = 0.f; ssq[t] = 0.f;
    }
#pragma unroll
    for (int i = 0; i < 16; i++) { int idx = t + i * 256; Wl[idx >> 6][idx & 63] = W[idx]; }
    __syncthreads();

    const int rbase = blockIdx.x * 64;
    {
        const int d = t & 63;
        float sc = 0.f, sh = 0.f;
        if (TRN) { sc = scl[d]; sh = shl[d]; }
#pragma unroll
        for (int i = 0; i < 16; i++) {
            int r = (t >> 6) + i * 4;
            float v = in[(size_t)(rbase + r) * 64 + d];
            if (TRN) v = fmaxf(fmaf(v, sc, sh), 0.f);
            inl[r][d] = v;
        }
    }
    __syncthreads();

    const int c0 = (t & 15) * 4, r0 = (t >> 4) * 4;
    float acc[4][4] = {};
#pragma unroll 16
    for (int d = 0; d < 64; d++) {
        float4 w4 = *(const float4*)&Wl[d][c0];
#pragma unroll
        for (int i = 0; i < 4; i++) {
            float h = inl[r0 + i][d];
            acc[i][0] = fmaf(h, w4.x, acc[i][0]);
            acc[i][1] = fmaf(h, w4.y, acc[i][1]);
            acc[i][2] = fmaf(h, w4.z, acc[i][2]);
            acc[i][3] = fmaf(h, w4.w, acc[i][3]);
        }
    }
#pragma unroll
    for (int i = 0; i < 4; i++) {
        float4 o; o.x = acc[i][0]; o.y = acc[i][1]; o.z = acc[i][2]; o.w = acc[i][3];
        *(float4*)&out[(size_t)(rbase + r0 + i) * 64 + c0] = o;
    }
    if (Sout) {
#pragma unroll
        for (int j = 0; j < 4; j++) {
            float s  = acc[0][j] + acc[1][j] + acc[2][j] + acc[3][j];
            float qv = acc[0][j] * acc[0][j] + acc[1][j] * acc[1][j] + acc[2][j] * acc[2][j] + acc[3][j] * acc[3][j];
            atomicAdd(&ssum[c0 + j], s);
            atomicAdd(&ssq[c0 + j], qv);
        }
        __syncthreads();
        if (t < 64) { atomicAdd(&Sout[t], ssum[t]); atomicAdd(&Sout[64 + t], ssq[t]); }
    }
}

// q4[e] = {q0,q1,q2, as_float(src[e])} (AoS float4); raw stats (3 cols) — 6 atomics/BLOCK.
__global__ __launch_bounds__(256) void edge_q_k(
    const float* __restrict__ pos, const int* __restrict__ src,
    const float* __restrict__ Wp1, const float* __restrict__ bp1,
    float4* __restrict__ q4, float* __restrict__ Sq)
{
    float w00 = Wp1[0], w01 = Wp1[1], w02 = Wp1[2];
    float w10 = Wp1[3], w11 = Wp1[4], w12 = Wp1[5];
    float w20 = Wp1[6], w21 = Wp1[7], w22 = Wp1[8];
    float c0 = bp1[0], c1 = bp1[1], c2 = bp1[2];
    float s0 = 0, s1 = 0, s2 = 0, p0 = 0, p1 = 0, p2 = 0;
    for (int e = blockIdx.x * blockDim.x + threadIdx.x; e < EE; e += gridDim.x * blockDim.x) {
        int sj = src[e]; int di = e >> 4;
        float r0 = pos[di * 3 + 0] - pos[sj * 3 + 0];
        float r1 = pos[di * 3 + 1] - pos[sj * 3 + 1];
        float r2 = pos[di * 3 + 2] - pos[sj * 3 + 2];
        float v0 = c0 + r0 * w00 + r1 * w10 + r2 * w20;
        float v1 = c1 + r0 * w01 + r1 * w11 + r2 * w21;
        float v2 = c2 + r0 * w02 + r1 * w12 + r2 * w22;
        float4 o; o.x = v0; o.y = v1; o.z = v2; o.w = __int_as_float(sj);
        q4[e] = o;
        s0 += v0; s1 += v1; s2 += v2;
        p0 += v0 * v0; p1 += v1 * v1; p2 += v2 * v2;
    }
#pragma unroll
    for (int o = 32; o > 0; o >>= 1) {
        s0 += __shfl_down(s0, o); s1 += __shfl_down(s1, o); s2 += __shfl_down(s2, o);
        p0 += __shfl_down(p0, o); p1 += __shfl_down(p1, o); p2 += __shfl_down(p2, o);
    }
    __shared__ float sred[4][6];
    const int w = threadIdx.x >> 6;
    if ((threadIdx.x & 63) == 0) {
        sred[w][0] = s0; sred[w][1] = s1; sred[w][2] = s2;
        sred[w][3] = p0; sred[w][4] = p1; sred[w][5] = p2;
    }
    __syncthreads();
    if (threadIdx.x < 6) {
        float v = sred[0][threadIdx.x] + sred[1][threadIdx.x] + sred[2][threadIdx.x] + sred[3][threadIdx.x];
        atomicAdd(&Sq[threadIdx.x], v);
    }
}

// Store-free raw column stats of a0 = a_dst[dst] - a_src[src] + delta  (64 cols over E rows).
// Wide-load node-per-wave: lane=(rowgrp r, featquad fq); 4 float4 asrc gathers + 1 q4 load.
__global__ __launch_bounds__(256) void edge_a0_k(
    const float4* __restrict__ q4v,
    const float* __restrict__ adst, const float* __restrict__ asrc,
    const float* __restrict__ Wp2, const float* __restrict__ bp2,
    const float* __restrict__ Sq, const float* __restrict__ gp, const float* __restrict__ bp_,
    float* __restrict__ Sa0)
{
    const int lane = threadIdx.x & 63;
    const int r = lane >> 4, fq = lane & 15;
    const int wv   = blockIdx.x * (blockDim.x >> 6) + (threadIdx.x >> 6);
    const int nwv  = gridDim.x * (blockDim.x >> 6);
    const float inv_e = 1.0f / (float)EE;
    float sc30, sh30, sc31, sh31, sc32, sh32;
    bn_coeff(Sq, 3, 0, gp, bp_, inv_e, sc30, sh30);
    bn_coeff(Sq, 3, 1, gp, bp_, inv_e, sc31, sh31);
    bn_coeff(Sq, 3, 2, gp, bp_, inv_e, sc32, sh32);
    float4 w0_4 = *(const float4*)&Wp2[fq * 4];
    float4 w1_4 = *(const float4*)&Wp2[64 + fq * 4];
    float4 w2_4 = *(const float4*)&Wp2[128 + fq * 4];
    float4 bd4  = *(const float4*)&bp2[fq * 4];
    float4 s4 = {0.f,0.f,0.f,0.f}, p4 = {0.f,0.f,0.f,0.f};

    for (int i = wv; i < NN; i += nwv) {
        const int e0 = i << 4;
        float4 ad4 = *(const float4*)&adst[(size_t)i * 64 + fq * 4];
        float4 qs  = q4v[e0 + (lane & 15)];
        int sv = __float_as_int(qs.w);
        int sj[4];
#pragma unroll
        for (int p = 0; p < 4; p++) sj[p] = __shfl(sv, p * 4 + r);
        float4 av[4];
#pragma unroll
        for (int p = 0; p < 4; p++) av[p] = *(const float4*)&asrc[(size_t)sj[p] * 64 + fq * 4];
#pragma unroll
        for (int p = 0; p < 4; p++) {
            int j = p * 4 + r;
            float ph0 = fmaxf(fmaf(__shfl(qs.x, j), sc30, sh30), 0.f);
            float ph1 = fmaxf(fmaf(__shfl(qs.y, j), sc31, sh31), 0.f);
            float ph2 = fmaxf(fmaf(__shfl(qs.z, j), sc32, sh32), 0.f);
            float4 a0v;
            a0v.x = ad4.x - av[p].x + bd4.x + ph0 * w0_4.x + ph1 * w1_4.x + ph2 * w2_4.x;
            a0v.y = ad4.y - av[p].y + bd4.y + ph0 * w0_4.y + ph1 * w1_4.y + ph2 * w2_4.y;
            a0v.z = ad4.z - av[p].z + bd4.z + ph0 * w0_4.z + ph1 * w1_4.z + ph2 * w2_4.z;
            a0v.w = ad4.w - av[p].w + bd4.w + ph0 * w0_4.w + ph1 * w1_4.w + ph2 * w2_4.w;
            s4.x += a0v.x; s4.y += a0v.y; s4.z += a0v.z; s4.w += a0v.w;
            p4.x = fmaf(a0v.x, a0v.x, p4.x); p4.y = fmaf(a0v.y, a0v.y, p4.y);
            p4.z = fmaf(a0v.z, a0v.z, p4.z); p4.w = fmaf(a0v.w, a0v.w, p4.w);
        }
    }
    s4.x += __shfl_xor(s4.x, 16); s4.y += __shfl_xor(s4.y, 16);
    s4.z += __shfl_xor(s4.z, 16); s4.w += __shfl_xor(s4.w, 16);
    p4.x += __shfl_xor(p4.x, 16); p4.y += __shfl_xor(p4.y, 16);
    p4.z += __shfl_xor(p4.z, 16); p4.w += __shfl_xor(p4.w, 16);
    s4.x += __shfl_xor(s4.x, 32); s4.y += __shfl_xor(s4.y, 32);
    s4.z += __shfl_xor(s4.z, 32); s4.w += __shfl_xor(s4.w, 32);
    p4.x += __shfl_xor(p4.x, 32); p4.y += __shfl_xor(p4.y, 32);
    p4.z += __shfl_xor(p4.z, 32); p4.w += __shfl_xor(p4.w, 32);

    __shared__ float ls[64], lq[64];
    if (threadIdx.x < 64) { ls[threadIdx.x] = 0.f; lq[threadIdx.x] = 0.f; }
    __syncthreads();
    if (lane < 16) {
        atomicAdd(&ls[fq * 4 + 0], s4.x); atomicAdd(&ls[fq * 4 + 1], s4.y);
        atomicAdd(&ls[fq * 4 + 2], s4.z); atomicAdd(&ls[fq * 4 + 3], s4.w);
        atomicAdd(&lq[fq * 4 + 0], p4.x); atomicAdd(&lq[fq * 4 + 1], p4.y);
        atomicAdd(&lq[fq * 4 + 2], p4.z); atomicAdd(&lq[fq * 4 + 3], p4.w);
    }
    __syncthreads();
    if (threadIdx.x < 64) { atomicAdd(&Sa0[threadIdx.x], ls[threadIdx.x]); atomicAdd(&Sa0[64 + threadIdx.x], lq[threadIdx.x]); }
}

// t = relu(bn(a0)) @ Wa1 + ba1  [E,8] — barrier-free node-per-wave:
// staging = a0's wide-gather recipe; GEMM in-register (lane holds 4 features' weights),
// K-reduce via shfl_xor over the 16 fq lanes; output via tiny wave-private LDS tile.
__global__ __launch_bounds__(256) void edge_t_k(
    const float4* __restrict__ q4v,
    const float* __restrict__ adst, const float* __restrict__ asrc,
    const float* __restrict__ Wp2, const float* __restrict__ bp2,
    const float* __restrict__ Sq, const float* __restrict__ gp, const float* __restrict__ bp_,
    const float* __restrict__ Sa0, const float* __restrict__ ga0, const float* __restrict__ ba0,
    const float* __restrict__ Wa1, const float* __restrict__ ba1,
    float* __restrict__ tout, float* __restrict__ St)
{
    __shared__ float t_l[4][16][8];     // wave-private output tile
    __shared__ float red[16];
    const int t = threadIdx.x, lane = t & 63, w = t >> 6;
    const int r = lane >> 4, fq = lane & 15;
    const int wv  = blockIdx.x * 4 + w;
    const int nwv = gridDim.x * 4;
    const float inv_e = 1.0f / (float)EE;
    float sc30, sh30, sc31, sh31, sc32, sh32;
    bn_coeff(Sq, 3, 0, gp, bp_, inv_e, sc30, sh30);
    bn_coeff(Sq, 3, 1, gp, bp_, inv_e, sc31, sh31);
    bn_coeff(Sq, 3, 2, gp, bp_, inv_e, sc32, sh32);
    float4 scA4, shA4;
    bn_coeff(Sa0, 64, fq * 4 + 0, ga0, ba0, inv_e, scA4.x, shA4.x);
    bn_coeff(Sa0, 64, fq * 4 + 1, ga0, ba0, inv_e, scA4.y, shA4.y);
    bn_coeff(Sa0, 64, fq * 4 + 2, ga0, ba0, inv_e, scA4.z, shA4.z);
    bn_coeff(Sa0, 64, fq * 4 + 3, ga0, ba0, inv_e, scA4.w, shA4.w);
    float4 w0_4 = *(const float4*)&Wp2[fq * 4];
    float4 w1_4 = *(const float4*)&Wp2[64 + fq * 4];
    float4 w2_4 = *(const float4*)&Wp2[128 + fq * 4];
    float4 bd4  = *(const float4*)&bp2[fq * 4];
    // Wa1 rows for this lane's 4 features (all 8 outputs)
    float wAf[4][8];
#pragma unroll
    for (int d = 0; d < 4; d++) {
        float4 lo = *(const float4*)&Wa1[(size_t)(fq * 4 + d) * 8];
        float4 hi = *(const float4*)&Wa1[(size_t)(fq * 4 + d) * 8 + 4];
        wAf[d][0] = lo.x; wAf[d][1] = lo.y; wAf[d][2] = lo.z; wAf[d][3] = lo.w;
        wAf[d][4] = hi.x; wAf[d][5] = hi.y; wAf[d][6] = hi.z; wAf[d][7] = hi.w;
    }
    float bb[8];
    {
        float4 lo = *(const float4*)&ba1[0];
        float4 hi = *(const float4*)&ba1[4];
        bb[0] = lo.x; bb[1] = lo.y; bb[2] = lo.z; bb[3] = lo.w;
        bb[4] = hi.x; bb[5] = hi.y; bb[6] = hi.z; bb[7] = hi.w;
    }
    float ss[8] = {}, sp[8] = {};
    if (t < 16) red[t] = 0.f;
    __syncthreads();

    for (int i = wv; i < NN; i += nwv) {
        const int e0 = i << 4;
        float4 ad4 = *(const float4*)&adst[(size_t)i * 64 + fq * 4];
        float4 qs  = q4v[e0 + (lane & 15)];
        int sv = __float_as_int(qs.w);
        int sj[4];
#pragma unroll
        for (int p = 0; p < 4; p++) sj[p] = __shfl(sv, p * 4 + r);
        float4 av[4];
#pragma unroll
        for (int p = 0; p < 4; p++) av[p] = *(const float4*)&asrc[(size_t)sj[p] * 64 + fq * 4];
#pragma unroll
        for (int p = 0; p < 4; p++) {
            int j = p * 4 + r;
            float ph0 = fmaxf(fmaf(__shfl(qs.x, j), sc30, sh30), 0.f);
            float ph1 = fmaxf(fmaf(__shfl(qs.y, j), sc31, sh31), 0.f);
            float ph2 = fmaxf(fmaf(__shfl(qs.z, j), sc32, sh32), 0.f);
            float4 a1v;
            a1v.x = ad4.x - av[p].x + bd4.x + ph0 * w0_4.x + ph1 * w1_4.x + ph2 * w2_4.x;
            a1v.y = ad4.y - av[p].y + bd4.y + ph0 * w0_4.y + ph1 * w1_4.y + ph2 * w2_4.y;
            a1v.z = ad4.z - av[p].z + bd4.z + ph0 * w0_4.z + ph1 * w1_4.z + ph2 * w2_4.z;
            a1v.w = ad4.w - av[p].w + bd4.w + ph0 * w0_4.w + ph1 * w1_4.w + ph2 * w2_4.w;
            a1v.x = fmaxf(fmaf(a1v.x, scA4.x, shA4.x), 0.f);
            a1v.y = fmaxf(fmaf(a1v.y, scA4.y, shA4.y), 0.f);
            a1v.z = fmaxf(fmaf(a1v.z, scA4.z, shA4.z), 0.f);
            a1v.w = fmaxf(fmaf(a1v.w, scA4.w, shA4.w), 0.f);
            float part[8];
#pragma unroll
            for (int k = 0; k < 8; k++) {
                part[k] = a1v.x * wAf[0][k] + a1v.y * wAf[1][k]
                        + a1v.z * wAf[2][k] + a1v.w * wAf[3][k];
            }
            // K-reduce over the 16 fq lanes (lane bits 0..3)
#pragma unroll
            for (int k = 0; k < 8; k++) {
                part[k] += __shfl_xor(part[k], 1);
                part[k] += __shfl_xor(part[k], 2);
                part[k] += __shfl_xor(part[k], 4);
                part[k] += __shfl_xor(part[k], 8);
            }
            if (fq == 0) {
#pragma unroll
                for (int k = 0; k < 8; k++) {
                    float v = part[k] + bb[k];
                    t_l[w][p * 4 + r][k] = v;
                    ss[k] += v; sp[k] = fmaf(v, v, sp[k]);
                }
            }
        }
        // wave-local readback (same-wave LDS ordering; no block barrier needed)
        float2 o = *(const float2*)&t_l[w][lane >> 2][(lane & 3) * 2];
        *(float2*)&tout[(size_t)e0 * 8 + lane * 2] = o;
    }
    // stats: fq==0 lanes hold partials; reduce across r (bits 4,5)
#pragma unroll
    for (int k = 0; k < 8; k++) {
        ss[k] += __shfl_xor(ss[k], 16); ss[k] += __shfl_xor(ss[k], 32);
        sp[k] += __shfl_xor(sp[k], 16); sp[k] += __shfl_xor(sp[k], 32);
    }
    if (lane == 0) {
#pragma unroll
        for (int k = 0; k < 8; k++) { atomicAdd(&red[k], ss[k]); atomicAdd(&red[8 + k], sp[k]); }
    }
    __syncthreads();
    if (t < 16) atomicAdd(&St[t], red[t]);
}

// Per-node (wave): a2=relu(bn(t)); a3=a2@Wa2+ba2; softmax; agg — wide-load edition.
__global__ __launch_bounds__(256) void edge_final_k(
    const float* __restrict__ tin,
    const float4* __restrict__ q4v, const float* __restrict__ vv,
    const float* __restrict__ Wp2, const float* __restrict__ bp2,
    const float* __restrict__ Sq, const float* __restrict__ gp, const float* __restrict__ bp_,
    const float* __restrict__ St, const float* __restrict__ ga1, const float* __restrict__ bb1,
    const float* __restrict__ Wa2, const float* __restrict__ ba2,
    float* __restrict__ agg, float* __restrict__ Sagg)
{
    __shared__ float att_l[4][16][68];   // wave-private attn (normalized), padded
    __shared__ float tt_l[4][16][8];     // wave-private tt tile
    __shared__ float ls[64], lq[64];
    const int t = threadIdx.x, lane = t & 63, w = t >> 6;
    const int r = lane >> 4, fq = lane & 15;
    const float inv_e = 1.0f / (float)EE;
    float sc3[3], sh3[3];
#pragma unroll
    for (int k = 0; k < 3; k++) bn_coeff(Sq, 3, k, gp, bp_, inv_e, sc3[k], sh3[k]);
    float sc8[8], sh8[8];
#pragma unroll
    for (int k = 0; k < 8; k++) bn_coeff(St, 8, k, ga1, bb1, inv_e, sc8[k], sh8[k]);
    float wa[8];
#pragma unroll
    for (int k = 0; k < 8; k++) wa[k] = Wa2[k * 64 + lane];
    float bad = ba2[lane];
    float4 wp0_4 = *(const float4*)&Wp2[fq * 4];
    float4 wp1_4 = *(const float4*)&Wp2[64 + fq * 4];
    float4 wp2_4 = *(const float4*)&Wp2[128 + fq * 4];
    float4 bpd4  = *(const float4*)&bp2[fq * 4];
    float4 ssum4 = {0.f, 0.f, 0.f, 0.f}, ssq4 = {0.f, 0.f, 0.f, 0.f};

    for (int nn = 0; nn < 4; nn++) {
        const int i  = blockIdx.x * 16 + nn * 4 + w;
        const int e0 = i << 4;
        if (lane < 32) {
            float4 v = *(const float4*)&tin[(size_t)e0 * 8 + lane * 4];
            ((float4*)&tt_l[w][0][0])[lane] = v;
        }
        float4 qs = q4v[e0 + (lane & 15)];
        int sv = __float_as_int(qs.w);
        __syncthreads();
        {
            float ax[16];
            float m = -3.0e38f;
#pragma unroll
            for (int j = 0; j < 16; j++) {
                float4 ta = *(const float4*)&tt_l[w][j][0];
                float4 tb = *(const float4*)&tt_l[w][j][4];
                float a = bad;
                a = fmaf(fmaxf(fmaf(ta.x, sc8[0], sh8[0]), 0.f), wa[0], a);
                a = fmaf(fmaxf(fmaf(ta.y, sc8[1], sh8[1]), 0.f), wa[1], a);
                a = fmaf(fmaxf(fmaf(ta.z, sc8[2], sh8[2]), 0.f), wa[2], a);
                a = fmaf(fmaxf(fmaf(ta.w, sc8[3], sh8[3]), 0.f), wa[3], a);
                a = fmaf(fmaxf(fmaf(tb.x, sc8[4], sh8[4]), 0.f), wa[4], a);
                a = fmaf(fmaxf(fmaf(tb.y, sc8[5], sh8[5]), 0.f), wa[5], a);
                a = fmaf(fmaxf(fmaf(tb.z, sc8[6], sh8[6]), 0.f), wa[6], a);
                a = fmaf(fmaxf(fmaf(tb.w, sc8[7], sh8[7]), 0.f), wa[7], a);
                ax[j] = a; m = fmaxf(m, a);
            }
            float s = 0.f;
#pragma unroll
            for (int j = 0; j < 16; j++) { ax[j] = __expf(ax[j] - m); s += ax[j]; }
            float inv = 1.0f / (s + 1e-16f);
#pragma unroll
            for (int j = 0; j < 16; j++) att_l[w][j][lane] = ax[j] * inv;
        }
        __syncthreads();
        {
            float4 acc = {0.f, 0.f, 0.f, 0.f};
#pragma unroll
            for (int p = 0; p < 4; p++) {
                int j  = p * 4 + r;
                int sj = __shfl(sv, j);
                float4 v4  = *(const float4*)&vv[(size_t)sj * 64 + fq * 4];
                float4 at4 = *(const float4*)&att_l[w][j][fq * 4];
                float ph0 = fmaxf(fmaf(__shfl(qs.x, j), sc3[0], sh3[0]), 0.f);
                float ph1 = fmaxf(fmaf(__shfl(qs.y, j), sc3[1], sh3[1]), 0.f);
                float ph2 = fmaxf(fmaf(__shfl(qs.z, j), sc3[2], sh3[2]), 0.f);
                float4 dl4;
                dl4.x = bpd4.x + ph0 * wp0_4.x + ph1 * wp1_4.x + ph2 * wp2_4.x;
                dl4.y = bpd4.y + ph0 * wp0_4.y + ph1 * wp1_4.y + ph2 * wp2_4.y;
                dl4.z = bpd4.z + ph0 * wp0_4.z + ph1 * wp1_4.z + ph2 * wp2_4.z;
                dl4.w = bpd4.w + ph0 * wp0_4.w + ph1 * wp1_4.w + ph2 * wp2_4.w;
                acc.x = fmaf(at4.x, v4.x + dl4.x, acc.x);
                acc.y = fmaf(at4.y, v4.y + dl4.y, acc.y);
                acc.z = fmaf(at4.z, v4.z + dl4.z, acc.z);
                acc.w = fmaf(at4.w, v4.w + dl4.w, acc.w);
            }
            acc.x += __shfl_xor(acc.x, 16); acc.y += __shfl_xor(acc.y, 16);
            acc.z += __shfl_xor(acc.z, 16); acc.w += __shfl_xor(acc.w, 16);
            acc.x += __shfl_xor(acc.x, 32); acc.y += __shfl_xor(acc.y, 32);
            acc.z += __shfl_xor(acc.z, 32); acc.w += __shfl_xor(acc.w, 32);
            if (lane < 16) {
                *(float4*)&agg[(size_t)i * 64 + lane * 4] = acc;
                ssum4.x += acc.x; ssum4.y += acc.y; ssum4.z += acc.z; ssum4.w += acc.w;
                ssq4.x  += acc.x * acc.x; ssq4.y += acc.y * acc.y;
                ssq4.z  += acc.z * acc.z; ssq4.w += acc.w * acc.w;
            }
        }
        __syncthreads();
    }
    if (t < 64) { ls[t] = 0.f; lq[t] = 0.f; }
    __syncthreads();
    if (lane < 16) {
        atomicAdd(&ls[fq * 4 + 0], ssum4.x); atomicAdd(&ls[fq * 4 + 1], ssum4.y);
        atomicAdd(&ls[fq * 4 + 2], ssum4.z); atomicAdd(&ls[fq * 4 + 3], ssum4.w);
        atomicAdd(&lq[fq * 4 + 0], ssq4.x);  atomicAdd(&lq[fq * 4 + 1], ssq4.y);
        atomicAdd(&lq[fq * 4 + 2], ssq4.z);  atomicAdd(&lq[fq * 4 + 3], ssq4.w);
    }
    __syncthreads();
    if (t < 64) { atomicAdd(&Sagg[t], ls[t]); atomicAdd(&Sagg[64 + t], lq[t]); }
}

// out = relu(bn(t2,g3,b3) + x)
__global__ __launch_bounds__(256) void final_k(
    const float* __restrict__ t2, const float* __restrict__ x,
    const float* __restrict__ St2, const float* __restrict__ g3, const float* __restrict__ b3,
    float* __restrict__ out)
{
    __shared__ float scl[64], shl[64];
    const int t = threadIdx.x;
    if (t < 64) { float sc, sh; bn_coeff(St2, 64, t, g3, b3, 1.0f / (float)NN, sc, sh); scl[t] = sc; shl[t] = sh; }
    __syncthreads();
    int idx = blockIdx.x * 256 + t;          // float4 index; NN*64/4 = 640000 exactly
    int c0 = (idx & 15) * 4;
    const float4 a = *(const float4*)&t2[(size_t)idx * 4];
    const float4 b = *(const float4*)&x[(size_t)idx * 4];
    float4 o;
    o.x = fmaxf(fmaf(a.x, scl[c0 + 0], shl[c0 + 0]) + b.x, 0.f);
    o.y = fmaxf(fmaf(a.y, scl[c0 + 1], shl[c0 + 1]) + b.y, 0.f);
    o.z = fmaxf(fmaf(a.z, scl[c0 + 2], shl[c0 + 2]) + b.z, 0.f);
    o.w = fmaxf(fmaf(a.w, scl[c0 + 3], shl[c0 + 3]) + b.w, 0.f);
    *(float4*)&out[(size_t)idx * 4] = o;
}

extern "C" void kernel_launch(void* const* d_in, const int* in_sizes, int n_in,
                              void* d_out, int out_size, void* d_ws, size_t ws_size,
                              hipStream_t stream)
{
    const float* x    = (const float*)d_in[0];
    const float* pos  = (const float*)d_in[1];
    const int*   src  = (const int*)d_in[2];      // edge_index[0]; dst[e] == e>>4 by construction
    const float* W_in = (const float*)d_in[3];
    const float* g1   = (const float*)d_in[4];
    const float* b1   = (const float*)d_in[5];
    const float* W_v  = (const float*)d_in[6];
    const float* W_src= (const float*)d_in[7];
    const float* W_dst= (const float*)d_in[8];
    const float* Wp1  = (const float*)d_in[9];
    const float* bp1  = (const float*)d_in[10];
    const float* gp   = (const float*)d_in[11];
    const float* bp_  = (const float*)d_in[12];
    const float* Wp2  = (const float*)d_in[13];
    const float* bp2  = (const float*)d_in[14];
    const float* ga0  = (const float*)d_in[15];
    const float* ba0  = (const float*)d_in[16];
    const float* Wa1  = (const float*)d_in[17];
    const float* ba1  = (const float*)d_in[18];
    const float* ga1  = (const float*)d_in[19];
    const float* bb1  = (const float*)d_in[20];
    const float* Wa2  = (const float*)d_in[21];
    const float* ba2  = (const float*)d_in[22];
    const float* g2   = (const float*)d_in[23];
    const float* b2   = (const float*)d_in[24];
    const float* W_out= (const float*)d_in[25];
    const float* g3   = (const float*)d_in[26];
    const float* b3   = (const float*)d_in[27];
    float* out = (float*)d_out;

    float* wsf   = (float*)d_ws;
    float* S_t1  = wsf;          // 128
    float* S_q   = wsf + 128;    // 6 used
    float* S_a0  = wsf + 192;    // 128
    float* S_t   = wsf + 320;    // 16 used
    float* S_agg = wsf + 384;    // 128
    float* S_t2  = wsf + 512;    // 128
    const size_t N64 = (size_t)NN * 64;
    float* t1   = wsf + 1024;
    float* asrc = t1 + N64;
    float* adst = asrc + N64;
    float* vv   = adst + N64;
    float* q4   = vv + N64;            // [E] float4 (q0,q1,q2,src)
    float* tt   = q4 + 4 * (size_t)EE; // [E,8]
    float* agg  = t1;            // alias: t1 dead after gemm #2
    float* t2   = asrc;          // alias: asrc dead after edge_t

    hipMemsetAsync(wsf, 0, 1024 * sizeof(float), stream);

    // t1 = x @ W_in (+stats)
    gemm64_k<0><<<dim3(625, 1), 256, 0, stream>>>(x, W_in, W_in, W_in, t1, t1, t1,
                                                  nullptr, nullptr, nullptr, 0.f, S_t1);
    // h = relu(bn(t1)); {asrc,adst,vv} = h @ {W_src,W_dst,W_v}
    gemm64_k<1><<<dim3(625, 3), 256, 0, stream>>>(t1, W_src, W_dst, W_v, asrc, adst, vv,
                                                  S_t1, g1, b1, 1.0f / (float)NN, nullptr);
    // q4 = {q, src} packed (+stats3)
    edge_q_k<<<256, 256, 0, stream>>>(pos, src, Wp1, bp1, (float4*)q4, S_q);
    // raw stats of a0 (store-free) — wide-load node-per-wave
    edge_a0_k<<<2048, 256, 0, stream>>>((const float4*)q4, adst, asrc, Wp2, bp2, S_q, gp, bp_, S_a0);
    // t = relu(bn(a0)) @ Wa1 + ba1 (+stats8) — barrier-free shfl-GEMM
    edge_t_k<<<2048, 256, 0, stream>>>((const float4*)q4, adst, asrc, Wp2, bp2, S_q, gp, bp_,
                                       S_a0, ga0, ba0, Wa1, ba1, tt, S_t);
    // a2,a3,softmax,agg (+stats) — wide-load structure
    edge_final_k<<<2500, 256, 0, stream>>>(tt, (const float4*)q4, vv, Wp2, bp2, S_q, gp, bp_,
                                           S_t, ga1, bb1, Wa2, ba2, agg, S_agg);
    // t2 = relu(bn(agg,g2,b2)) @ W_out (+stats)
    gemm64_k<1><<<dim3(625, 1), 256, 0, stream>>>(agg, W_out, W_out, W_out, t2, t2, t2,
                                                  S_agg, g2, b2, 1.0f / (float)NN, S_t2);
    // out = relu(bn(t2,g3,b3) + x)
    final_k<<<2500, 256, 0, stream>>>(t2, x, S_t2, g3, b3, out);
}

// Round 15
// 290.868 us; speedup vs baseline: 1.1086x; 1.1086x over previous
//
#include <hip/hip_runtime.h>

#define NN 40000
#define DDIM 64
#define KE 16
#define EE 640000
#define BNEPS 1e-5f

#define WAVE_FENCE() asm volatile("" ::: "memory")

// Finalize BN coefficients from raw sums: stats layout [sum[C], sumsq[C]].
__device__ __forceinline__ void bn_coeff(const float* __restrict__ S, int C, int c,
                                         const float* __restrict__ g, const float* __restrict__ b,
                                         float inv_n, float& sc, float& sh)
{
    float m   = S[c] * inv_n;
    float var = S[C + c] * inv_n - m * m;
    float r   = rsqrtf(var + BNEPS);
    sc = g[c] * r;
    sh = b[c] - m * sc;
}

// out[r][c] = sum_d f(in[r][d]) * W[d][c], 64x64 W, optional BN+ReLU input transform,
// optional raw column-stats accumulation on the output.
template<int TRN>
__global__ __launch_bounds__(256) void gemm64_k(
    const float* __restrict__ in,
    const float* __restrict__ W0, const float* __restrict__ W1, const float* __restrict__ W2,
    float* __restrict__ out0, float* __restrict__ out1, float* __restrict__ out2,
    const float* __restrict__ Sin, const float* __restrict__ gamma, const float* __restrict__ beta,
    float inv_n, float* __restrict__ Sout)
{
    const float* W = (blockIdx.y == 0) ? W0 : ((blockIdx.y == 1) ? W1 : W2);
    float* out     = (blockIdx.y == 0) ? out0 : ((blockIdx.y == 1) ? out1 : out2);

    __shared__ float Wl[64][64];
    __shared__ float inl[64][65];
    __shared__ float scl[64], shl[64];
    __shared__ float ssum[64], ssq[64];

    const int t = threadIdx.x;
    if (t < 64) {
        if (TRN) { float sc, sh; bn_coeff(Sin, 64, t, gamma, beta, inv_n, sc, sh); scl[t] = sc; shl[t] = sh; }
        ssum[t] = 0.f; ssq[t] = 0.f;
    }
#pragma unroll
    for (int i = 0; i < 16; i++) { int idx = t + i * 256; Wl[idx >> 6][idx & 63] = W[idx]; }
    __syncthreads();

    const int rbase = blockIdx.x * 64;
    {
        const int d = t & 63;
        float sc = 0.f, sh = 0.f;
        if (TRN) { sc = scl[d]; sh = shl[d]; }
#pragma unroll
        for (int i = 0; i < 16; i++) {
            int r = (t >> 6) + i * 4;
            float v = in[(size_t)(rbase + r) * 64 + d];
            if (TRN) v = fmaxf(fmaf(v, sc, sh), 0.f);
            inl[r][d] = v;
        }
    }
    __syncthreads();

    const int c0 = (t & 15) * 4, r0 = (t >> 4) * 4;
    float acc[4][4] = {};
#pragma unroll 16
    for (int d = 0; d < 64; d++) {
        float4 w4 = *(const float4*)&Wl[d][c0];
#pragma unroll
        for (int i = 0; i < 4; i++) {
            float h = inl[r0 + i][d];
            acc[i][0] = fmaf(h, w4.x, acc[i][0]);
            acc[i][1] = fmaf(h, w4.y, acc[i][1]);
            acc[i][2] = fmaf(h, w4.z, acc[i][2]);
            acc[i][3] = fmaf(h, w4.w, acc[i][3]);
        }
    }
#pragma unroll
    for (int i = 0; i < 4; i++) {
        float4 o; o.x = acc[i][0]; o.y = acc[i][1]; o.z = acc[i][2]; o.w = acc[i][3];
        *(float4*)&out[(size_t)(rbase + r0 + i) * 64 + c0] = o;
    }
    if (Sout) {
#pragma unroll
        for (int j = 0; j < 4; j++) {
            float s  = acc[0][j] + acc[1][j] + acc[2][j] + acc[3][j];
            float qv = acc[0][j] * acc[0][j] + acc[1][j] * acc[1][j] + acc[2][j] * acc[2][j] + acc[3][j] * acc[3][j];
            atomicAdd(&ssum[c0 + j], s);
            atomicAdd(&ssq[c0 + j], qv);
        }
        __syncthreads();
        if (t < 64) { atomicAdd(&Sout[t], ssum[t]); atomicAdd(&Sout[64 + t], ssq[t]); }
    }
}

// q4[e] = {q0,q1,q2, as_float(src[e])} (AoS float4); raw stats (3 cols) — 6 atomics/BLOCK.
__global__ __launch_bounds__(256) void edge_q_k(
    const float* __restrict__ pos, const int* __restrict__ src,
    const float* __restrict__ Wp1, const float* __restrict__ bp1,
    float4* __restrict__ q4, float* __restrict__ Sq)
{
    float w00 = Wp1[0], w01 = Wp1[1], w02 = Wp1[2];
    float w10 = Wp1[3], w11 = Wp1[4], w12 = Wp1[5];
    float w20 = Wp1[6], w21 = Wp1[7], w22 = Wp1[8];
    float c0 = bp1[0], c1 = bp1[1], c2 = bp1[2];
    float s0 = 0, s1 = 0, s2 = 0, p0 = 0, p1 = 0, p2 = 0;
    for (int e = blockIdx.x * blockDim.x + threadIdx.x; e < EE; e += gridDim.x * blockDim.x) {
        int sj = src[e]; int di = e >> 4;
        float r0 = pos[di * 3 + 0] - pos[sj * 3 + 0];
        float r1 = pos[di * 3 + 1] - pos[sj * 3 + 1];
        float r2 = pos[di * 3 + 2] - pos[sj * 3 + 2];
        float v0 = c0 + r0 * w00 + r1 * w10 + r2 * w20;
        float v1 = c1 + r0 * w01 + r1 * w11 + r2 * w21;
        float v2 = c2 + r0 * w02 + r1 * w12 + r2 * w22;
        float4 o; o.x = v0; o.y = v1; o.z = v2; o.w = __int_as_float(sj);
        q4[e] = o;
        s0 += v0; s1 += v1; s2 += v2;
        p0 += v0 * v0; p1 += v1 * v1; p2 += v2 * v2;
    }
#pragma unroll
    for (int o = 32; o > 0; o >>= 1) {
        s0 += __shfl_down(s0, o); s1 += __shfl_down(s1, o); s2 += __shfl_down(s2, o);
        p0 += __shfl_down(p0, o); p1 += __shfl_down(p1, o); p2 += __shfl_down(p2, o);
    }
    __shared__ float sred[4][6];
    const int w = threadIdx.x >> 6;
    if ((threadIdx.x & 63) == 0) {
        sred[w][0] = s0; sred[w][1] = s1; sred[w][2] = s2;
        sred[w][3] = p0; sred[w][4] = p1; sred[w][5] = p2;
    }
    __syncthreads();
    if (threadIdx.x < 6) {
        float v = sred[0][threadIdx.x] + sred[1][threadIdx.x] + sred[2][threadIdx.x] + sred[3][threadIdx.x];
        atomicAdd(&Sq[threadIdx.x], v);
    }
}

// Store-free raw column stats of a0 = a_dst[dst] - a_src[src] + delta  (64 cols over E rows).
// Wide-load node-per-wave: lane=(rowgrp r, featquad fq); 4 float4 asrc gathers + 1 q4 load.
__global__ __launch_bounds__(256) void edge_a0_k(
    const float4* __restrict__ q4v,
    const float* __restrict__ adst, const float* __restrict__ asrc,
    const float* __restrict__ Wp2, const float* __restrict__ bp2,
    const float* __restrict__ Sq, const float* __restrict__ gp, const float* __restrict__ bp_,
    float* __restrict__ Sa0)
{
    const int lane = threadIdx.x & 63;
    const int r = lane >> 4, fq = lane & 15;
    const int wv   = blockIdx.x * (blockDim.x >> 6) + (threadIdx.x >> 6);
    const int nwv  = gridDim.x * (blockDim.x >> 6);
    const float inv_e = 1.0f / (float)EE;
    float sc30, sh30, sc31, sh31, sc32, sh32;
    bn_coeff(Sq, 3, 0, gp, bp_, inv_e, sc30, sh30);
    bn_coeff(Sq, 3, 1, gp, bp_, inv_e, sc31, sh31);
    bn_coeff(Sq, 3, 2, gp, bp_, inv_e, sc32, sh32);
    float4 w0_4 = *(const float4*)&Wp2[fq * 4];
    float4 w1_4 = *(const float4*)&Wp2[64 + fq * 4];
    float4 w2_4 = *(const float4*)&Wp2[128 + fq * 4];
    float4 bd4  = *(const float4*)&bp2[fq * 4];
    float4 s4 = {0.f,0.f,0.f,0.f}, p4 = {0.f,0.f,0.f,0.f};

    for (int i = wv; i < NN; i += nwv) {
        const int e0 = i << 4;
        float4 ad4 = *(const float4*)&adst[(size_t)i * 64 + fq * 4];
        float4 qs  = q4v[e0 + (lane & 15)];
        int sv = __float_as_int(qs.w);
        int sj[4];
#pragma unroll
        for (int p = 0; p < 4; p++) sj[p] = __shfl(sv, p * 4 + r);
        float4 av[4];
#pragma unroll
        for (int p = 0; p < 4; p++) av[p] = *(const float4*)&asrc[(size_t)sj[p] * 64 + fq * 4];
#pragma unroll
        for (int p = 0; p < 4; p++) {
            int j = p * 4 + r;
            float ph0 = fmaxf(fmaf(__shfl(qs.x, j), sc30, sh30), 0.f);
            float ph1 = fmaxf(fmaf(__shfl(qs.y, j), sc31, sh31), 0.f);
            float ph2 = fmaxf(fmaf(__shfl(qs.z, j), sc32, sh32), 0.f);
            float4 a0v;
            a0v.x = ad4.x - av[p].x + bd4.x + ph0 * w0_4.x + ph1 * w1_4.x + ph2 * w2_4.x;
            a0v.y = ad4.y - av[p].y + bd4.y + ph0 * w0_4.y + ph1 * w1_4.y + ph2 * w2_4.y;
            a0v.z = ad4.z - av[p].z + bd4.z + ph0 * w0_4.z + ph1 * w1_4.z + ph2 * w2_4.z;
            a0v.w = ad4.w - av[p].w + bd4.w + ph0 * w0_4.w + ph1 * w1_4.w + ph2 * w2_4.w;
            s4.x += a0v.x; s4.y += a0v.y; s4.z += a0v.z; s4.w += a0v.w;
            p4.x = fmaf(a0v.x, a0v.x, p4.x); p4.y = fmaf(a0v.y, a0v.y, p4.y);
            p4.z = fmaf(a0v.z, a0v.z, p4.z); p4.w = fmaf(a0v.w, a0v.w, p4.w);
        }
    }
    s4.x += __shfl_xor(s4.x, 16); s4.y += __shfl_xor(s4.y, 16);
    s4.z += __shfl_xor(s4.z, 16); s4.w += __shfl_xor(s4.w, 16);
    p4.x += __shfl_xor(p4.x, 16); p4.y += __shfl_xor(p4.y, 16);
    p4.z += __shfl_xor(p4.z, 16); p4.w += __shfl_xor(p4.w, 16);
    s4.x += __shfl_xor(s4.x, 32); s4.y += __shfl_xor(s4.y, 32);
    s4.z += __shfl_xor(s4.z, 32); s4.w += __shfl_xor(s4.w, 32);
    p4.x += __shfl_xor(p4.x, 32); p4.y += __shfl_xor(p4.y, 32);
    p4.z += __shfl_xor(p4.z, 32); p4.w += __shfl_xor(p4.w, 32);

    __shared__ float ls[64], lq[64];
    if (threadIdx.x < 64) { ls[threadIdx.x] = 0.f; lq[threadIdx.x] = 0.f; }
    __syncthreads();
    if (lane < 16) {
        atomicAdd(&ls[fq * 4 + 0], s4.x); atomicAdd(&ls[fq * 4 + 1], s4.y);
        atomicAdd(&ls[fq * 4 + 2], s4.z); atomicAdd(&ls[fq * 4 + 3], s4.w);
        atomicAdd(&lq[fq * 4 + 0], p4.x); atomicAdd(&lq[fq * 4 + 1], p4.y);
        atomicAdd(&lq[fq * 4 + 2], p4.z); atomicAdd(&lq[fq * 4 + 3], p4.w);
    }
    __syncthreads();
    if (threadIdx.x < 64) { atomicAdd(&Sa0[threadIdx.x], ls[threadIdx.x]); atomicAdd(&Sa0[64 + threadIdx.x], lq[threadIdx.x]); }
}

// t = relu(bn(a0)) @ Wa1 + ba1  [E,8] — wide-load staging + wave-private LDS-GEMM.
// Wave w owns node i and LDS slice a1l[w*16..w*16+15]; NO block barriers in the loop.
__global__ __launch_bounds__(256) void edge_t_k(
    const float4* __restrict__ q4v,
    const float* __restrict__ adst, const float* __restrict__ asrc,
    const float* __restrict__ Wp2, const float* __restrict__ bp2,
    const float* __restrict__ Sq, const float* __restrict__ gp, const float* __restrict__ bp_,
    const float* __restrict__ Sa0, const float* __restrict__ ga0, const float* __restrict__ ba0,
    const float* __restrict__ Wa1, const float* __restrict__ ba1,
    float* __restrict__ tout, float* __restrict__ St)
{
    __shared__ float a1l[64][68];
    __shared__ float wl[64][8];
    __shared__ float red[16];
    const int t = threadIdx.x, lane = t & 63, w = t >> 6;
    const int r = lane >> 4, fq = lane & 15;
    const float inv_e = 1.0f / (float)EE;
    float sc30, sh30, sc31, sh31, sc32, sh32;
    bn_coeff(Sq, 3, 0, gp, bp_, inv_e, sc30, sh30);
    bn_coeff(Sq, 3, 1, gp, bp_, inv_e, sc31, sh31);
    bn_coeff(Sq, 3, 2, gp, bp_, inv_e, sc32, sh32);
    float4 scA4, shA4;
    bn_coeff(Sa0, 64, fq * 4 + 0, ga0, ba0, inv_e, scA4.x, shA4.x);
    bn_coeff(Sa0, 64, fq * 4 + 1, ga0, ba0, inv_e, scA4.y, shA4.y);
    bn_coeff(Sa0, 64, fq * 4 + 2, ga0, ba0, inv_e, scA4.z, shA4.z);
    bn_coeff(Sa0, 64, fq * 4 + 3, ga0, ba0, inv_e, scA4.w, shA4.w);
    float4 w0_4 = *(const float4*)&Wp2[fq * 4];
    float4 w1_4 = *(const float4*)&Wp2[64 + fq * 4];
    float4 w2_4 = *(const float4*)&Wp2[128 + fq * 4];
    float4 bd4  = *(const float4*)&bp2[fq * 4];
    for (int i = t; i < 512; i += 256) wl[i >> 3][i & 7] = Wa1[i];
    if (t < 16) red[t] = 0.f;
    __syncthreads();

    const int eLl = lane >> 2;            // local edge within wave slice (0..15)
    const int j0  = (lane & 3) * 2;       // output pair
    float bA = ba1[j0], bB = ba1[j0 + 1];
    float ssA = 0.f, spA = 0.f, ssB = 0.f, spB = 0.f;

    for (int i = blockIdx.x * 4 + w; i < NN; i += gridDim.x * 4) {
        const int e0 = i << 4;
        {   // stage: 4 float4 asrc gathers + 1 q4 load + 1 adst load → a1l[w*16+j]
            float4 ad4 = *(const float4*)&adst[(size_t)i * 64 + fq * 4];
            float4 qs  = q4v[e0 + (lane & 15)];
            int sv = __float_as_int(qs.w);
            int sj[4];
#pragma unroll
            for (int p = 0; p < 4; p++) sj[p] = __shfl(sv, p * 4 + r);
            float4 av[4];
#pragma unroll
            for (int p = 0; p < 4; p++) av[p] = *(const float4*)&asrc[(size_t)sj[p] * 64 + fq * 4];
#pragma unroll
            for (int p = 0; p < 4; p++) {
                int j = p * 4 + r;
                float ph0 = fmaxf(fmaf(__shfl(qs.x, j), sc30, sh30), 0.f);
                float ph1 = fmaxf(fmaf(__shfl(qs.y, j), sc31, sh31), 0.f);
                float ph2 = fmaxf(fmaf(__shfl(qs.z, j), sc32, sh32), 0.f);
                float4 a1v;
                a1v.x = ad4.x - av[p].x + bd4.x + ph0 * w0_4.x + ph1 * w1_4.x + ph2 * w2_4.x;
                a1v.y = ad4.y - av[p].y + bd4.y + ph0 * w0_4.y + ph1 * w1_4.y + ph2 * w2_4.y;
                a1v.z = ad4.z - av[p].z + bd4.z + ph0 * w0_4.z + ph1 * w1_4.z + ph2 * w2_4.z;
                a1v.w = ad4.w - av[p].w + bd4.w + ph0 * w0_4.w + ph1 * w1_4.w + ph2 * w2_4.w;
                a1v.x = fmaxf(fmaf(a1v.x, scA4.x, shA4.x), 0.f);
                a1v.y = fmaxf(fmaf(a1v.y, scA4.y, shA4.y), 0.f);
                a1v.z = fmaxf(fmaf(a1v.z, scA4.z, shA4.z), 0.f);
                a1v.w = fmaxf(fmaf(a1v.w, scA4.w, shA4.w), 0.f);
                *(float4*)&a1l[w * 16 + j][fq * 4] = a1v;
            }
        }
        WAVE_FENCE();   // wave-private LDS: compiler fence only, no block barrier
        {   // GEMM over this wave's slice: t[e][j0], t[e][j0+1]
            float acc0 = bA, acc1 = bB;
#pragma unroll 16
            for (int dd = 0; dd < 64; dd++) {
                float a = a1l[w * 16 + eLl][dd];
                acc0 = fmaf(a, wl[dd][j0], acc0);
                acc1 = fmaf(a, wl[dd][j0 + 1], acc1);
            }
            int e = e0 + eLl;
            float2 o; o.x = acc0; o.y = acc1;
            *(float2*)&tout[(size_t)e * 8 + j0] = o;
            ssA += acc0; spA += acc0 * acc0;
            ssB += acc1; spB += acc1 * acc1;
        }
        WAVE_FENCE();   // order GEMM reads before next iteration's staging writes
    }
    __syncthreads();
    atomicAdd(&red[j0], ssA);     atomicAdd(&red[j0 + 1], ssB);
    atomicAdd(&red[8 + j0], spA); atomicAdd(&red[8 + j0 + 1], spB);
    __syncthreads();
    if (t < 16) atomicAdd(&St[t], red[t]);
}

// Per-node (wave): a2=relu(bn(t)); a3=a2@Wa2+ba2; softmax; agg — wide-load, barrier-free loop.
__global__ __launch_bounds__(256) void edge_final_k(
    const float* __restrict__ tin,
    const float4* __restrict__ q4v, const float* __restrict__ vv,
    const float* __restrict__ Wp2, const float* __restrict__ bp2,
    const float* __restrict__ Sq, const float* __restrict__ gp, const float* __restrict__ bp_,
    const float* __restrict__ St, const float* __restrict__ ga1, const float* __restrict__ bb1,
    const float* __restrict__ Wa2, const float* __restrict__ ba2,
    float* __restrict__ agg, float* __restrict__ Sagg)
{
    __shared__ float att_l[4][16][68];   // wave-private attn (normalized), padded
    __shared__ float tt_l[4][16][8];     // wave-private tt tile
    __shared__ float ls[64], lq[64];
    const int t = threadIdx.x, lane = t & 63, w = t >> 6;
    const int r = lane >> 4, fq = lane & 15;
    const float inv_e = 1.0f / (float)EE;
    float sc3[3], sh3[3];
#pragma unroll
    for (int k = 0; k < 3; k++) bn_coeff(Sq, 3, k, gp, bp_, inv_e, sc3[k], sh3[k]);
    float sc8[8], sh8[8];
#pragma unroll
    for (int k = 0; k < 8; k++) bn_coeff(St, 8, k, ga1, bb1, inv_e, sc8[k], sh8[k]);
    float wa[8];
#pragma unroll
    for (int k = 0; k < 8; k++) wa[k] = Wa2[k * 64 + lane];
    float bad = ba2[lane];
    float4 wp0_4 = *(const float4*)&Wp2[fq * 4];
    float4 wp1_4 = *(const float4*)&Wp2[64 + fq * 4];
    float4 wp2_4 = *(const float4*)&Wp2[128 + fq * 4];
    float4 bpd4  = *(const float4*)&bp2[fq * 4];
    float4 ssum4 = {0.f, 0.f, 0.f, 0.f}, ssq4 = {0.f, 0.f, 0.f, 0.f};

    for (int nn = 0; nn < 4; nn++) {
        const int i  = blockIdx.x * 16 + nn * 4 + w;
        const int e0 = i << 4;
        if (lane < 32) {
            float4 v = *(const float4*)&tin[(size_t)e0 * 8 + lane * 4];
            ((float4*)&tt_l[w][0][0])[lane] = v;
        }
        float4 qs = q4v[e0 + (lane & 15)];
        int sv = __float_as_int(qs.w);
        WAVE_FENCE();   // wave-private tt_l: compiler fence, no block barrier
        {
            float ax[16];
            float m = -3.0e38f;
#pragma unroll
            for (int j = 0; j < 16; j++) {
                float4 ta = *(const float4*)&tt_l[w][j][0];
                float4 tb = *(const float4*)&tt_l[w][j][4];
                float a = bad;
                a = fmaf(fmaxf(fmaf(ta.x, sc8[0], sh8[0]), 0.f), wa[0], a);
                a = fmaf(fmaxf(fmaf(ta.y, sc8[1], sh8[1]), 0.f), wa[1], a);
                a = fmaf(fmaxf(fmaf(ta.z, sc8[2], sh8[2]), 0.f), wa[2], a);
                a = fmaf(fmaxf(fmaf(ta.w, sc8[3], sh8[3]), 0.f), wa[3], a);
                a = fmaf(fmaxf(fmaf(tb.x, sc8[4], sh8[4]), 0.f), wa[4], a);
                a = fmaf(fmaxf(fmaf(tb.y, sc8[5], sh8[5]), 0.f), wa[5], a);
                a = fmaf(fmaxf(fmaf(tb.z, sc8[6], sh8[6]), 0.f), wa[6], a);
                a = fmaf(fmaxf(fmaf(tb.w, sc8[7], sh8[7]), 0.f), wa[7], a);
                ax[j] = a; m = fmaxf(m, a);
            }
            float s = 0.f;
#pragma unroll
            for (int j = 0; j < 16; j++) { ax[j] = __expf(ax[j] - m); s += ax[j]; }
            float inv = 1.0f / (s + 1e-16f);
#pragma unroll
            for (int j = 0; j < 16; j++) att_l[w][j][lane] = ax[j] * inv;
        }
        WAVE_FENCE();   // wave-private att_l
        {
            float4 acc = {0.f, 0.f, 0.f, 0.f};
#pragma unroll
            for (int p = 0; p < 4; p++) {
                int j  = p * 4 + r;
                int sj = __shfl(sv, j);
                float4 v4  = *(const float4*)&vv[(size_t)sj * 64 + fq * 4];
                float4 at4 = *(const float4*)&att_l[w][j][fq * 4];
                float ph0 = fmaxf(fmaf(__shfl(qs.x, j), sc3[0], sh3[0]), 0.f);
                float ph1 = fmaxf(fmaf(__shfl(qs.y, j), sc3[1], sh3[1]), 0.f);
                float ph2 = fmaxf(fmaf(__shfl(qs.z, j), sc3[2], sh3[2]), 0.f);
                float4 dl4;
                dl4.x = bpd4.x + ph0 * wp0_4.x + ph1 * wp1_4.x + ph2 * wp2_4.x;
                dl4.y = bpd4.y + ph0 * wp0_4.y + ph1 * wp1_4.y + ph2 * wp2_4.y;
                dl4.z = bpd4.z + ph0 * wp0_4.z + ph1 * wp1_4.z + ph2 * wp2_4.z;
                dl4.w = bpd4.w + ph0 * wp0_4.w + ph1 * wp1_4.w + ph2 * wp2_4.w;
                acc.x = fmaf(at4.x, v4.x + dl4.x, acc.x);
                acc.y = fmaf(at4.y, v4.y + dl4.y, acc.y);
                acc.z = fmaf(at4.z, v4.z + dl4.z, acc.z);
                acc.w = fmaf(at4.w, v4.w + dl4.w, acc.w);
            }
            acc.x += __shfl_xor(acc.x, 16); acc.y += __shfl_xor(acc.y, 16);
            acc.z += __shfl_xor(acc.z, 16); acc.w += __shfl_xor(acc.w, 16);
            acc.x += __shfl_xor(acc.x, 32); acc.y += __shfl_xor(acc.y, 32);
            acc.z += __shfl_xor(acc.z, 32); acc.w += __shfl_xor(acc.w, 32);
            if (lane < 16) {
                *(float4*)&agg[(size_t)i * 64 + lane * 4] = acc;
                ssum4.x += acc.x; ssum4.y += acc.y; ssum4.z += acc.z; ssum4.w += acc.w;
                ssq4.x  += acc.x * acc.x; ssq4.y += acc.y * acc.y;
                ssq4.z  += acc.z * acc.z; ssq4.w += acc.w * acc.w;
            }
        }
        WAVE_FENCE();   // order phase-2 reads before next iteration's writes
    }
    if (t < 64) { ls[t] = 0.f; lq[t] = 0.f; }
    __syncthreads();
    if (lane < 16) {
        atomicAdd(&ls[fq * 4 + 0], ssum4.x); atomicAdd(&ls[fq * 4 + 1], ssum4.y);
        atomicAdd(&ls[fq * 4 + 2], ssum4.z); atomicAdd(&ls[fq * 4 + 3], ssum4.w);
        atomicAdd(&lq[fq * 4 + 0], ssq4.x);  atomicAdd(&lq[fq * 4 + 1], ssq4.y);
        atomicAdd(&lq[fq * 4 + 2], ssq4.z);  atomicAdd(&lq[fq * 4 + 3], ssq4.w);
    }
    __syncthreads();
    if (t < 64) { atomicAdd(&Sagg[t], ls[t]); atomicAdd(&Sagg[64 + t], lq[t]); }
}

// out = relu(bn(t2,g3,b3) + x)
__global__ __launch_bounds__(256) void final_k(
    const float* __restrict__ t2, const float* __restrict__ x,
    const float* __restrict__ St2, const float* __restrict__ g3, const float* __restrict__ b3,
    float* __restrict__ out)
{
    __shared__ float scl[64], shl[64];
    const int t = threadIdx.x;
    if (t < 64) { float sc, sh; bn_coeff(St2, 64, t, g3, b3, 1.0f / (float)NN, sc, sh); scl[t] = sc; shl[t] = sh; }
    __syncthreads();
    int idx = blockIdx.x * 256 + t;          // float4 index; NN*64/4 = 640000 exactly
    int c0 = (idx & 15) * 4;
    const float4 a = *(const float4*)&t2[(size_t)idx * 4];
    const float4 b = *(const float4*)&x[(size_t)idx * 4];
    float4 o;
    o.x = fmaxf(fmaf(a.x, scl[c0 + 0], shl[c0 + 0]) + b.x, 0.f);
    o.y = fmaxf(fmaf(a.y, scl[c0 + 1], shl[c0 + 1]) + b.y, 0.f);
    o.z = fmaxf(fmaf(a.z, scl[c0 + 2], shl[c0 + 2]) + b.z, 0.f);
    o.w = fmaxf(fmaf(a.w, scl[c0 + 3], shl[c0 + 3]) + b.w, 0.f);
    *(float4*)&out[(size_t)idx * 4] = o;
}

extern "C" void kernel_launch(void* const* d_in, const int* in_sizes, int n_in,
                              void* d_out, int out_size, void* d_ws, size_t ws_size,
                              hipStream_t stream)
{
    const float* x    = (const float*)d_in[0];
    const float* pos  = (const float*)d_in[1];
    const int*   src  = (const int*)d_in[2];      // edge_index[0]; dst[e] == e>>4 by construction
    const float* W_in = (const float*)d_in[3];
    const float* g1   = (const float*)d_in[4];
    const float* b1   = (const float*)d_in[5];
    const float* W_v  = (const float*)d_in[6];
    const float* W_src= (const float*)d_in[7];
    const float* W_dst= (const float*)d_in[8];
    const float* Wp1  = (const float*)d_in[9];
    const float* bp1  = (const float*)d_in[10];
    const float* gp   = (const float*)d_in[11];
    const float* bp_  = (const float*)d_in[12];
    const float* Wp2  = (const float*)d_in[13];
    const float* bp2  = (const float*)d_in[14];
    const float* ga0  = (const float*)d_in[15];
    const float* ba0  = (const float*)d_in[16];
    const float* Wa1  = (const float*)d_in[17];
    const float* ba1  = (const float*)d_in[18];
    const float* ga1  = (const float*)d_in[19];
    const float* bb1  = (const float*)d_in[20];
    const float* Wa2  = (const float*)d_in[21];
    const float* ba2  = (const float*)d_in[22];
    const float* g2   = (const float*)d_in[23];
    const float* b2   = (const float*)d_in[24];
    const float* W_out= (const float*)d_in[25];
    const float* g3   = (const float*)d_in[26];
    const float* b3   = (const float*)d_in[27];
    float* out = (float*)d_out;

    float* wsf   = (float*)d_ws;
    float* S_t1  = wsf;          // 128
    float* S_q   = wsf + 128;    // 6 used
    float* S_a0  = wsf + 192;    // 128
    float* S_t   = wsf + 320;    // 16 used
    float* S_agg = wsf + 384;    // 128
    float* S_t2  = wsf + 512;    // 128
    const size_t N64 = (size_t)NN * 64;
    float* t1   = wsf + 1024;
    float* asrc = t1 + N64;
    float* adst = asrc + N64;
    float* vv   = adst + N64;
    float* q4   = vv + N64;            // [E] float4 (q0,q1,q2,src)
    float* tt   = q4 + 4 * (size_t)EE; // [E,8]
    float* agg  = t1;            // alias: t1 dead after gemm #2
    float* t2   = asrc;          // alias: asrc dead after edge_t

    hipMemsetAsync(wsf, 0, 1024 * sizeof(float), stream);

    // t1 = x @ W_in (+stats)
    gemm64_k<0><<<dim3(625, 1), 256, 0, stream>>>(x, W_in, W_in, W_in, t1, t1, t1,
                                                  nullptr, nullptr, nullptr, 0.f, S_t1);
    // h = relu(bn(t1)); {asrc,adst,vv} = h @ {W_src,W_dst,W_v}
    gemm64_k<1><<<dim3(625, 3), 256, 0, stream>>>(t1, W_src, W_dst, W_v, asrc, adst, vv,
                                                  S_t1, g1, b1, 1.0f / (float)NN, nullptr);
    // q4 = {q, src} packed (+stats3)
    edge_q_k<<<256, 256, 0, stream>>>(pos, src, Wp1, bp1, (float4*)q4, S_q);
    // raw stats of a0 (store-free) — wide-load node-per-wave
    edge_a0_k<<<2048, 256, 0, stream>>>((const float4*)q4, adst, asrc, Wp2, bp2, S_q, gp, bp_, S_a0);
    // t = relu(bn(a0)) @ Wa1 + ba1 (+stats8) — wave-private LDS-GEMM, barrier-free loop
    edge_t_k<<<2048, 256, 0, stream>>>((const float4*)q4, adst, asrc, Wp2, bp2, S_q, gp, bp_,
                                       S_a0, ga0, ba0, Wa1, ba1, tt, S_t);
    // a2,a3,softmax,agg (+stats) — wide-load, barrier-free loop
    edge_final_k<<<2500, 256, 0, stream>>>(tt, (const float4*)q4, vv, Wp2, bp2, S_q, gp, bp_,
                                           S_t, ga1, bb1, Wa2, ba2, agg, S_agg);
    // t2 = relu(bn(agg,g2,b2)) @ W_out (+stats)
    gemm64_k<1><<<dim3(625, 1), 256, 0, stream>>>(agg, W_out, W_out, W_out, t2, t2, t2,
                                                  S_agg, g2, b2, 1.0f / (float)NN, S_t2);
    // out = relu(bn(t2,g3,b3) + x)
    final_k<<<2500, 256, 0, stream>>>(t2, x, S_t2, g3, b3, out);
}

// Round 16
// 286.165 us; speedup vs baseline: 1.1268x; 1.0164x over previous
//
#include <hip/hip_runtime.h>

#define NN 40000
#define DDIM 64
#define KE 16
#define EE 640000
#define BNEPS 1e-5f

#define WAVE_FENCE() asm volatile("" ::: "memory")

// Finalize BN coefficients from raw sums: stats layout [sum[C], sumsq[C]].
__device__ __forceinline__ void bn_coeff(const float* __restrict__ S, int C, int c,
                                         const float* __restrict__ g, const float* __restrict__ b,
                                         float inv_n, float& sc, float& sh)
{
    float m   = S[c] * inv_n;
    float var = S[C + c] * inv_n - m * m;
    float r   = rsqrtf(var + BNEPS);
    sc = g[c] * r;
    sh = b[c] - m * sc;
}

// Fused launch: blocks [0,625) compute t1 = x @ W_in (+stats); blocks [625,785)
// compute q4 = {(pos[dst]-pos[src])@Wp1+bp1, src} (+stats3). Independent work.
__global__ __launch_bounds__(256) void gemm0q_k(
    const float* __restrict__ in, const float* __restrict__ W,
    float* __restrict__ out, float* __restrict__ Sout,
    const float* __restrict__ pos, const int* __restrict__ src,
    const float* __restrict__ Wp1, const float* __restrict__ bp1,
    float4* __restrict__ q4, float* __restrict__ Sq)
{
    const int t = threadIdx.x;
    if (blockIdx.x < 625) {
        __shared__ float Wl[64][64];
        __shared__ float inl[64][65];
        __shared__ float ssum[64], ssq[64];
        if (t < 64) { ssum[t] = 0.f; ssq[t] = 0.f; }
#pragma unroll
        for (int i = 0; i < 16; i++) { int idx = t + i * 256; Wl[idx >> 6][idx & 63] = W[idx]; }
        const int rbase = blockIdx.x * 64;
        {
            const int d = t & 63;
#pragma unroll
            for (int i = 0; i < 16; i++) {
                int r = (t >> 6) + i * 4;
                inl[r][d] = in[(size_t)(rbase + r) * 64 + d];
            }
        }
        __syncthreads();
        const int c0 = (t & 15) * 4, r0 = (t >> 4) * 4;
        float acc[4][4] = {};
#pragma unroll 16
        for (int d = 0; d < 64; d++) {
            float4 w4 = *(const float4*)&Wl[d][c0];
#pragma unroll
            for (int i = 0; i < 4; i++) {
                float h = inl[r0 + i][d];
                acc[i][0] = fmaf(h, w4.x, acc[i][0]);
                acc[i][1] = fmaf(h, w4.y, acc[i][1]);
                acc[i][2] = fmaf(h, w4.z, acc[i][2]);
                acc[i][3] = fmaf(h, w4.w, acc[i][3]);
            }
        }
#pragma unroll
        for (int i = 0; i < 4; i++) {
            float4 o; o.x = acc[i][0]; o.y = acc[i][1]; o.z = acc[i][2]; o.w = acc[i][3];
            *(float4*)&out[(size_t)(rbase + r0 + i) * 64 + c0] = o;
        }
#pragma unroll
        for (int j = 0; j < 4; j++) {
            float s  = acc[0][j] + acc[1][j] + acc[2][j] + acc[3][j];
            float qv = acc[0][j] * acc[0][j] + acc[1][j] * acc[1][j] + acc[2][j] * acc[2][j] + acc[3][j] * acc[3][j];
            atomicAdd(&ssum[c0 + j], s);
            atomicAdd(&ssq[c0 + j], qv);
        }
        __syncthreads();
        if (t < 64) { atomicAdd(&Sout[t], ssum[t]); atomicAdd(&Sout[64 + t], ssq[t]); }
    } else {
        __shared__ float sred[4][6];
        const int bq = blockIdx.x - 625;
        float w00 = Wp1[0], w01 = Wp1[1], w02 = Wp1[2];
        float w10 = Wp1[3], w11 = Wp1[4], w12 = Wp1[5];
        float w20 = Wp1[6], w21 = Wp1[7], w22 = Wp1[8];
        float c0 = bp1[0], c1 = bp1[1], c2 = bp1[2];
        float s0 = 0, s1 = 0, s2 = 0, p0 = 0, p1 = 0, p2 = 0;
        for (int e = bq * 256 + t; e < EE; e += 160 * 256) {
            int sj = src[e]; int di = e >> 4;
            float r0 = pos[di * 3 + 0] - pos[sj * 3 + 0];
            float r1 = pos[di * 3 + 1] - pos[sj * 3 + 1];
            float r2 = pos[di * 3 + 2] - pos[sj * 3 + 2];
            float v0 = c0 + r0 * w00 + r1 * w10 + r2 * w20;
            float v1 = c1 + r0 * w01 + r1 * w11 + r2 * w21;
            float v2 = c2 + r0 * w02 + r1 * w12 + r2 * w22;
            float4 o; o.x = v0; o.y = v1; o.z = v2; o.w = __int_as_float(sj);
            q4[e] = o;
            s0 += v0; s1 += v1; s2 += v2;
            p0 += v0 * v0; p1 += v1 * v1; p2 += v2 * v2;
        }
#pragma unroll
        for (int o = 32; o > 0; o >>= 1) {
            s0 += __shfl_down(s0, o); s1 += __shfl_down(s1, o); s2 += __shfl_down(s2, o);
            p0 += __shfl_down(p0, o); p1 += __shfl_down(p1, o); p2 += __shfl_down(p2, o);
        }
        const int w = t >> 6;
        if ((t & 63) == 0) {
            sred[w][0] = s0; sred[w][1] = s1; sred[w][2] = s2;
            sred[w][3] = p0; sred[w][4] = p1; sred[w][5] = p2;
        }
        __syncthreads();
        if (t < 6) {
            float v = sred[0][t] + sred[1][t] + sred[2][t] + sred[3][t];
            atomicAdd(&Sq[t], v);
        }
    }
}

// h = relu(bn(t1)) staged ONCE in LDS; three weight phases produce asrc/adst/vv.
__global__ __launch_bounds__(256) void gemm3_k(
    const float* __restrict__ in,
    const float* __restrict__ W0, const float* __restrict__ W1, const float* __restrict__ W2,
    float* __restrict__ out0, float* __restrict__ out1, float* __restrict__ out2,
    const float* __restrict__ Sin, const float* __restrict__ gamma, const float* __restrict__ beta,
    float inv_n)
{
    __shared__ float Wl[64][64];
    __shared__ float inl[64][65];
    __shared__ float scl[64], shl[64];
    const int t = threadIdx.x;
    if (t < 64) { float sc, sh; bn_coeff(Sin, 64, t, gamma, beta, inv_n, sc, sh); scl[t] = sc; shl[t] = sh; }
    __syncthreads();
    const int rbase = blockIdx.x * 64;
    {
        const int d = t & 63;
        float sc = scl[d], sh = shl[d];
#pragma unroll
        for (int i = 0; i < 16; i++) {
            int r = (t >> 6) + i * 4;
            float v = in[(size_t)(rbase + r) * 64 + d];
            inl[r][d] = fmaxf(fmaf(v, sc, sh), 0.f);
        }
    }
    const int c0 = (t & 15) * 4, r0 = (t >> 4) * 4;
#pragma unroll
    for (int ph = 0; ph < 3; ph++) {
        const float* W = (ph == 0) ? W0 : ((ph == 1) ? W1 : W2);
        float* out     = (ph == 0) ? out0 : ((ph == 1) ? out1 : out2);
        __syncthreads();   // previous phase's Wl reads done (and inl ready on ph 0)
#pragma unroll
        for (int i = 0; i < 16; i++) { int idx = t + i * 256; Wl[idx >> 6][idx & 63] = W[idx]; }
        __syncthreads();
        float acc[4][4] = {};
#pragma unroll 16
        for (int d = 0; d < 64; d++) {
            float4 w4 = *(const float4*)&Wl[d][c0];
#pragma unroll
            for (int i = 0; i < 4; i++) {
                float h = inl[r0 + i][d];
                acc[i][0] = fmaf(h, w4.x, acc[i][0]);
                acc[i][1] = fmaf(h, w4.y, acc[i][1]);
                acc[i][2] = fmaf(h, w4.z, acc[i][2]);
                acc[i][3] = fmaf(h, w4.w, acc[i][3]);
            }
        }
#pragma unroll
        for (int i = 0; i < 4; i++) {
            float4 o; o.x = acc[i][0]; o.y = acc[i][1]; o.z = acc[i][2]; o.w = acc[i][3];
            *(float4*)&out[(size_t)(rbase + r0 + i) * 64 + c0] = o;
        }
    }
}

// Generic single-output gemm with BN+ReLU input transform and output stats (last gemm).
__global__ __launch_bounds__(256) void gemm1_k(
    const float* __restrict__ in, const float* __restrict__ W,
    float* __restrict__ out,
    const float* __restrict__ Sin, const float* __restrict__ gamma, const float* __restrict__ beta,
    float inv_n, float* __restrict__ Sout)
{
    __shared__ float Wl[64][64];
    __shared__ float inl[64][65];
    __shared__ float scl[64], shl[64];
    __shared__ float ssum[64], ssq[64];
    const int t = threadIdx.x;
    if (t < 64) {
        float sc, sh; bn_coeff(Sin, 64, t, gamma, beta, inv_n, sc, sh); scl[t] = sc; shl[t] = sh;
        ssum[t] = 0.f; ssq[t] = 0.f;
    }
#pragma unroll
    for (int i = 0; i < 16; i++) { int idx = t + i * 256; Wl[idx >> 6][idx & 63] = W[idx]; }
    __syncthreads();
    const int rbase = blockIdx.x * 64;
    {
        const int d = t & 63;
        float sc = scl[d], sh = shl[d];
#pragma unroll
        for (int i = 0; i < 16; i++) {
            int r = (t >> 6) + i * 4;
            float v = in[(size_t)(rbase + r) * 64 + d];
            inl[r][d] = fmaxf(fmaf(v, sc, sh), 0.f);
        }
    }
    __syncthreads();
    const int c0 = (t & 15) * 4, r0 = (t >> 4) * 4;
    float acc[4][4] = {};
#pragma unroll 16
    for (int d = 0; d < 64; d++) {
        float4 w4 = *(const float4*)&Wl[d][c0];
#pragma unroll
        for (int i = 0; i < 4; i++) {
            float h = inl[r0 + i][d];
            acc[i][0] = fmaf(h, w4.x, acc[i][0]);
            acc[i][1] = fmaf(h, w4.y, acc[i][1]);
            acc[i][2] = fmaf(h, w4.z, acc[i][2]);
            acc[i][3] = fmaf(h, w4.w, acc[i][3]);
        }
    }
#pragma unroll
    for (int i = 0; i < 4; i++) {
        float4 o; o.x = acc[i][0]; o.y = acc[i][1]; o.z = acc[i][2]; o.w = acc[i][3];
        *(float4*)&out[(size_t)(rbase + r0 + i) * 64 + c0] = o;
    }
#pragma unroll
    for (int j = 0; j < 4; j++) {
        float s  = acc[0][j] + acc[1][j] + acc[2][j] + acc[3][j];
        float qv = acc[0][j] * acc[0][j] + acc[1][j] * acc[1][j] + acc[2][j] * acc[2][j] + acc[3][j] * acc[3][j];
        atomicAdd(&ssum[c0 + j], s);
        atomicAdd(&ssq[c0 + j], qv);
    }
    __syncthreads();
    if (t < 64) { atomicAdd(&Sout[t], ssum[t]); atomicAdd(&Sout[64 + t], ssq[t]); }
}

// Store-free raw column stats of a0 = a_dst[dst] - a_src[src] + delta  (64 cols over E rows).
// Wide-load node-per-wave: lane=(rowgrp r, featquad fq); 4 float4 asrc gathers + 1 q4 load.
__global__ __launch_bounds__(256) void edge_a0_k(
    const float4* __restrict__ q4v,
    const float* __restrict__ adst, const float* __restrict__ asrc,
    const float* __restrict__ Wp2, const float* __restrict__ bp2,
    const float* __restrict__ Sq, const float* __restrict__ gp, const float* __restrict__ bp_,
    float* __restrict__ Sa0)
{
    const int lane = threadIdx.x & 63;
    const int r = lane >> 4, fq = lane & 15;
    const int wv   = blockIdx.x * (blockDim.x >> 6) + (threadIdx.x >> 6);
    const int nwv  = gridDim.x * (blockDim.x >> 6);
    const float inv_e = 1.0f / (float)EE;
    float sc30, sh30, sc31, sh31, sc32, sh32;
    bn_coeff(Sq, 3, 0, gp, bp_, inv_e, sc30, sh30);
    bn_coeff(Sq, 3, 1, gp, bp_, inv_e, sc31, sh31);
    bn_coeff(Sq, 3, 2, gp, bp_, inv_e, sc32, sh32);
    float4 w0_4 = *(const float4*)&Wp2[fq * 4];
    float4 w1_4 = *(const float4*)&Wp2[64 + fq * 4];
    float4 w2_4 = *(const float4*)&Wp2[128 + fq * 4];
    float4 bd4  = *(const float4*)&bp2[fq * 4];
    float4 s4 = {0.f,0.f,0.f,0.f}, p4 = {0.f,0.f,0.f,0.f};

    for (int i = wv; i < NN; i += nwv) {
        const int e0 = i << 4;
        float4 ad4 = *(const float4*)&adst[(size_t)i * 64 + fq * 4];
        float4 qs  = q4v[e0 + (lane & 15)];
        int sv = __float_as_int(qs.w);
        int sj[4];
#pragma unroll
        for (int p = 0; p < 4; p++) sj[p] = __shfl(sv, p * 4 + r);
        float4 av[4];
#pragma unroll
        for (int p = 0; p < 4; p++) av[p] = *(const float4*)&asrc[(size_t)sj[p] * 64 + fq * 4];
#pragma unroll
        for (int p = 0; p < 4; p++) {
            int j = p * 4 + r;
            float ph0 = fmaxf(fmaf(__shfl(qs.x, j), sc30, sh30), 0.f);
            float ph1 = fmaxf(fmaf(__shfl(qs.y, j), sc31, sh31), 0.f);
            float ph2 = fmaxf(fmaf(__shfl(qs.z, j), sc32, sh32), 0.f);
            float4 a0v;
            a0v.x = ad4.x - av[p].x + bd4.x + ph0 * w0_4.x + ph1 * w1_4.x + ph2 * w2_4.x;
            a0v.y = ad4.y - av[p].y + bd4.y + ph0 * w0_4.y + ph1 * w1_4.y + ph2 * w2_4.y;
            a0v.z = ad4.z - av[p].z + bd4.z + ph0 * w0_4.z + ph1 * w1_4.z + ph2 * w2_4.z;
            a0v.w = ad4.w - av[p].w + bd4.w + ph0 * w0_4.w + ph1 * w1_4.w + ph2 * w2_4.w;
            s4.x += a0v.x; s4.y += a0v.y; s4.z += a0v.z; s4.w += a0v.w;
            p4.x = fmaf(a0v.x, a0v.x, p4.x); p4.y = fmaf(a0v.y, a0v.y, p4.y);
            p4.z = fmaf(a0v.z, a0v.z, p4.z); p4.w = fmaf(a0v.w, a0v.w, p4.w);
        }
    }
    s4.x += __shfl_xor(s4.x, 16); s4.y += __shfl_xor(s4.y, 16);
    s4.z += __shfl_xor(s4.z, 16); s4.w += __shfl_xor(s4.w, 16);
    p4.x += __shfl_xor(p4.x, 16); p4.y += __shfl_xor(p4.y, 16);
    p4.z += __shfl_xor(p4.z, 16); p4.w += __shfl_xor(p4.w, 16);
    s4.x += __shfl_xor(s4.x, 32); s4.y += __shfl_xor(s4.y, 32);
    s4.z += __shfl_xor(s4.z, 32); s4.w += __shfl_xor(s4.w, 32);
    p4.x += __shfl_xor(p4.x, 32); p4.y += __shfl_xor(p4.y, 32);
    p4.z += __shfl_xor(p4.z, 32); p4.w += __shfl_xor(p4.w, 32);

    __shared__ float ls[64], lq[64];
    if (threadIdx.x < 64) { ls[threadIdx.x] = 0.f; lq[threadIdx.x] = 0.f; }
    __syncthreads();
    if (lane < 16) {
        atomicAdd(&ls[fq * 4 + 0], s4.x); atomicAdd(&ls[fq * 4 + 1], s4.y);
        atomicAdd(&ls[fq * 4 + 2], s4.z); atomicAdd(&ls[fq * 4 + 3], s4.w);
        atomicAdd(&lq[fq * 4 + 0], p4.x); atomicAdd(&lq[fq * 4 + 1], p4.y);
        atomicAdd(&lq[fq * 4 + 2], p4.z); atomicAdd(&lq[fq * 4 + 3], p4.w);
    }
    __syncthreads();
    if (threadIdx.x < 64) { atomicAdd(&Sa0[threadIdx.x], ls[threadIdx.x]); atomicAdd(&Sa0[64 + threadIdx.x], lq[threadIdx.x]); }
}

// t = relu(bn(a0)) @ Wa1 + ba1  [E,8] — wide-load staging + wave-private LDS-GEMM.
// Wave w owns node i and LDS slice a1l[w*16..w*16+15]; NO block barriers in the loop.
__global__ __launch_bounds__(256) void edge_t_k(
    const float4* __restrict__ q4v,
    const float* __restrict__ adst, const float* __restrict__ asrc,
    const float* __restrict__ Wp2, const float* __restrict__ bp2,
    const float* __restrict__ Sq, const float* __restrict__ gp, const float* __restrict__ bp_,
    const float* __restrict__ Sa0, const float* __restrict__ ga0, const float* __restrict__ ba0,
    const float* __restrict__ Wa1, const float* __restrict__ ba1,
    float* __restrict__ tout, float* __restrict__ St)
{
    __shared__ float a1l[64][68];
    __shared__ float wl[64][8];
    __shared__ float red[16];
    const int t = threadIdx.x, lane = t & 63, w = t >> 6;
    const int r = lane >> 4, fq = lane & 15;
    const float inv_e = 1.0f / (float)EE;
    float sc30, sh30, sc31, sh31, sc32, sh32;
    bn_coeff(Sq, 3, 0, gp, bp_, inv_e, sc30, sh30);
    bn_coeff(Sq, 3, 1, gp, bp_, inv_e, sc31, sh31);
    bn_coeff(Sq, 3, 2, gp, bp_, inv_e, sc32, sh32);
    float4 scA4, shA4;
    bn_coeff(Sa0, 64, fq * 4 + 0, ga0, ba0, inv_e, scA4.x, shA4.x);
    bn_coeff(Sa0, 64, fq * 4 + 1, ga0, ba0, inv_e, scA4.y, shA4.y);
    bn_coeff(Sa0, 64, fq * 4 + 2, ga0, ba0, inv_e, scA4.z, shA4.z);
    bn_coeff(Sa0, 64, fq * 4 + 3, ga0, ba0, inv_e, scA4.w, shA4.w);
    float4 w0_4 = *(const float4*)&Wp2[fq * 4];
    float4 w1_4 = *(const float4*)&Wp2[64 + fq * 4];
    float4 w2_4 = *(const float4*)&Wp2[128 + fq * 4];
    float4 bd4  = *(const float4*)&bp2[fq * 4];
    for (int i = t; i < 512; i += 256) wl[i >> 3][i & 7] = Wa1[i];
    if (t < 16) red[t] = 0.f;
    __syncthreads();

    const int eLl = lane >> 2;            // local edge within wave slice (0..15)
    const int j0  = (lane & 3) * 2;       // output pair
    float bA = ba1[j0], bB = ba1[j0 + 1];
    float ssA = 0.f, spA = 0.f, ssB = 0.f, spB = 0.f;

    for (int i = blockIdx.x * 4 + w; i < NN; i += gridDim.x * 4) {
        const int e0 = i << 4;
        {   // stage: 4 float4 asrc gathers + 1 q4 load + 1 adst load → a1l[w*16+j]
            float4 ad4 = *(const float4*)&adst[(size_t)i * 64 + fq * 4];
            float4 qs  = q4v[e0 + (lane & 15)];
            int sv = __float_as_int(qs.w);
            int sj[4];
#pragma unroll
            for (int p = 0; p < 4; p++) sj[p] = __shfl(sv, p * 4 + r);
            float4 av[4];
#pragma unroll
            for (int p = 0; p < 4; p++) av[p] = *(const float4*)&asrc[(size_t)sj[p] * 64 + fq * 4];
#pragma unroll
            for (int p = 0; p < 4; p++) {
                int j = p * 4 + r;
                float ph0 = fmaxf(fmaf(__shfl(qs.x, j), sc30, sh30), 0.f);
                float ph1 = fmaxf(fmaf(__shfl(qs.y, j), sc31, sh31), 0.f);
                float ph2 = fmaxf(fmaf(__shfl(qs.z, j), sc32, sh32), 0.f);
                float4 a1v;
                a1v.x = ad4.x - av[p].x + bd4.x + ph0 * w0_4.x + ph1 * w1_4.x + ph2 * w2_4.x;
                a1v.y = ad4.y - av[p].y + bd4.y + ph0 * w0_4.y + ph1 * w1_4.y + ph2 * w2_4.y;
                a1v.z = ad4.z - av[p].z + bd4.z + ph0 * w0_4.z + ph1 * w1_4.z + ph2 * w2_4.z;
                a1v.w = ad4.w - av[p].w + bd4.w + ph0 * w0_4.w + ph1 * w1_4.w + ph2 * w2_4.w;
                a1v.x = fmaxf(fmaf(a1v.x, scA4.x, shA4.x), 0.f);
                a1v.y = fmaxf(fmaf(a1v.y, scA4.y, shA4.y), 0.f);
                a1v.z = fmaxf(fmaf(a1v.z, scA4.z, shA4.z), 0.f);
                a1v.w = fmaxf(fmaf(a1v.w, scA4.w, shA4.w), 0.f);
                *(float4*)&a1l[w * 16 + j][fq * 4] = a1v;
            }
        }
        WAVE_FENCE();   // wave-private LDS: compiler fence only, no block barrier
        {   // GEMM over this wave's slice: t[e][j0], t[e][j0+1]
            float acc0 = bA, acc1 = bB;
#pragma unroll 16
            for (int dd = 0; dd < 64; dd++) {
                float a = a1l[w * 16 + eLl][dd];
                acc0 = fmaf(a, wl[dd][j0], acc0);
                acc1 = fmaf(a, wl[dd][j0 + 1], acc1);
            }
            int e = e0 + eLl;
            float2 o; o.x = acc0; o.y = acc1;
            *(float2*)&tout[(size_t)e * 8 + j0] = o;
            ssA += acc0; spA += acc0 * acc0;
            ssB += acc1; spB += acc1 * acc1;
        }
        WAVE_FENCE();   // order GEMM reads before next iteration's staging writes
    }
    __syncthreads();
    atomicAdd(&red[j0], ssA);     atomicAdd(&red[j0 + 1], ssB);
    atomicAdd(&red[8 + j0], spA); atomicAdd(&red[8 + j0 + 1], spB);
    __syncthreads();
    if (t < 16) atomicAdd(&St[t], red[t]);
}

// Per-node (wave): a2=relu(bn(t)); a3=a2@Wa2+ba2; softmax; agg — wide-load, barrier-free loop.
__global__ __launch_bounds__(256) void edge_final_k(
    const float* __restrict__ tin,
    const float4* __restrict__ q4v, const float* __restrict__ vv,
    const float* __restrict__ Wp2, const float* __restrict__ bp2,
    const float* __restrict__ Sq, const float* __restrict__ gp, const float* __restrict__ bp_,
    const float* __restrict__ St, const float* __restrict__ ga1, const float* __restrict__ bb1,
    const float* __restrict__ Wa2, const float* __restrict__ ba2,
    float* __restrict__ agg, float* __restrict__ Sagg)
{
    __shared__ float att_l[4][16][68];   // wave-private attn (normalized), padded
    __shared__ float tt_l[4][16][8];     // wave-private tt tile
    __shared__ float ls[64], lq[64];
    const int t = threadIdx.x, lane = t & 63, w = t >> 6;
    const int r = lane >> 4, fq = lane & 15;
    const float inv_e = 1.0f / (float)EE;
    float sc3[3], sh3[3];
#pragma unroll
    for (int k = 0; k < 3; k++) bn_coeff(Sq, 3, k, gp, bp_, inv_e, sc3[k], sh3[k]);
    float sc8[8], sh8[8];
#pragma unroll
    for (int k = 0; k < 8; k++) bn_coeff(St, 8, k, ga1, bb1, inv_e, sc8[k], sh8[k]);
    float wa[8];
#pragma unroll
    for (int k = 0; k < 8; k++) wa[k] = Wa2[k * 64 + lane];
    float bad = ba2[lane];
    float4 wp0_4 = *(const float4*)&Wp2[fq * 4];
    float4 wp1_4 = *(const float4*)&Wp2[64 + fq * 4];
    float4 wp2_4 = *(const float4*)&Wp2[128 + fq * 4];
    float4 bpd4  = *(const float4*)&bp2[fq * 4];
    float4 ssum4 = {0.f, 0.f, 0.f, 0.f}, ssq4 = {0.f, 0.f, 0.f, 0.f};

    for (int nn = 0; nn < 4; nn++) {
        const int i  = blockIdx.x * 16 + nn * 4 + w;
        const int e0 = i << 4;
        if (lane < 32) {
            float4 v = *(const float4*)&tin[(size_t)e0 * 8 + lane * 4];
            ((float4*)&tt_l[w][0][0])[lane] = v;
        }
        float4 qs = q4v[e0 + (lane & 15)];
        int sv = __float_as_int(qs.w);
        WAVE_FENCE();   // wave-private tt_l: compiler fence, no block barrier
        {
            float ax[16];
            float m = -3.0e38f;
#pragma unroll
            for (int j = 0; j < 16; j++) {
                float4 ta = *(const float4*)&tt_l[w][j][0];
                float4 tb = *(const float4*)&tt_l[w][j][4];
                float a = bad;
                a = fmaf(fmaxf(fmaf(ta.x, sc8[0], sh8[0]), 0.f), wa[0], a);
                a = fmaf(fmaxf(fmaf(ta.y, sc8[1], sh8[1]), 0.f), wa[1], a);
                a = fmaf(fmaxf(fmaf(ta.z, sc8[2], sh8[2]), 0.f), wa[2], a);
                a = fmaf(fmaxf(fmaf(ta.w, sc8[3], sh8[3]), 0.f), wa[3], a);
                a = fmaf(fmaxf(fmaf(tb.x, sc8[4], sh8[4]), 0.f), wa[4], a);
                a = fmaf(fmaxf(fmaf(tb.y, sc8[5], sh8[5]), 0.f), wa[5], a);
                a = fmaf(fmaxf(fmaf(tb.z, sc8[6], sh8[6]), 0.f), wa[6], a);
                a = fmaf(fmaxf(fmaf(tb.w, sc8[7], sh8[7]), 0.f), wa[7], a);
                ax[j] = a; m = fmaxf(m, a);
            }
            float s = 0.f;
#pragma unroll
            for (int j = 0; j < 16; j++) { ax[j] = __expf(ax[j] - m); s += ax[j]; }
            float inv = 1.0f / (s + 1e-16f);
#pragma unroll
            for (int j = 0; j < 16; j++) att_l[w][j][lane] = ax[j] * inv;
        }
        WAVE_FENCE();   // wave-private att_l
        {
            float4 acc = {0.f, 0.f, 0.f, 0.f};
#pragma unroll
            for (int p = 0; p < 4; p++) {
                int j  = p * 4 + r;
                int sj = __shfl(sv, j);
                float4 v4  = *(const float4*)&vv[(size_t)sj * 64 + fq * 4];
                float4 at4 = *(const float4*)&att_l[w][j][fq * 4];
                float ph0 = fmaxf(fmaf(__shfl(qs.x, j), sc3[0], sh3[0]), 0.f);
                float ph1 = fmaxf(fmaf(__shfl(qs.y, j), sc3[1], sh3[1]), 0.f);
                float ph2 = fmaxf(fmaf(__shfl(qs.z, j), sc3[2], sh3[2]), 0.f);
                float4 dl4;
                dl4.x = bpd4.x + ph0 * wp0_4.x + ph1 * wp1_4.x + ph2 * wp2_4.x;
                dl4.y = bpd4.y + ph0 * wp0_4.y + ph1 * wp1_4.y + ph2 * wp2_4.y;
                dl4.z = bpd4.z + ph0 * wp0_4.z + ph1 * wp1_4.z + ph2 * wp2_4.z;
                dl4.w = bpd4.w + ph0 * wp0_4.w + ph1 * wp1_4.w + ph2 * wp2_4.w;
                acc.x = fmaf(at4.x, v4.x + dl4.x, acc.x);
                acc.y = fmaf(at4.y, v4.y + dl4.y, acc.y);
                acc.z = fmaf(at4.z, v4.z + dl4.z, acc.z);
                acc.w = fmaf(at4.w, v4.w + dl4.w, acc.w);
            }
            acc.x += __shfl_xor(acc.x, 16); acc.y += __shfl_xor(acc.y, 16);
            acc.z += __shfl_xor(acc.z, 16); acc.w += __shfl_xor(acc.w, 16);
            acc.x += __shfl_xor(acc.x, 32); acc.y += __shfl_xor(acc.y, 32);
            acc.z += __shfl_xor(acc.z, 32); acc.w += __shfl_xor(acc.w, 32);
            if (lane < 16) {
                *(float4*)&agg[(size_t)i * 64 + lane * 4] = acc;
                ssum4.x += acc.x; ssum4.y += acc.y; ssum4.z += acc.z; ssum4.w += acc.w;
                ssq4.x  += acc.x * acc.x; ssq4.y += acc.y * acc.y;
                ssq4.z  += acc.z * acc.z; ssq4.w += acc.w * acc.w;
            }
        }
        WAVE_FENCE();   // order phase-2 reads before next iteration's writes
    }
    if (t < 64) { ls[t] = 0.f; lq[t] = 0.f; }
    __syncthreads();
    if (lane < 16) {
        atomicAdd(&ls[fq * 4 + 0], ssum4.x); atomicAdd(&ls[fq * 4 + 1], ssum4.y);
        atomicAdd(&ls[fq * 4 + 2], ssum4.z); atomicAdd(&ls[fq * 4 + 3], ssum4.w);
        atomicAdd(&lq[fq * 4 + 0], ssq4.x);  atomicAdd(&lq[fq * 4 + 1], ssq4.y);
        atomicAdd(&lq[fq * 4 + 2], ssq4.z);  atomicAdd(&lq[fq * 4 + 3], ssq4.w);
    }
    __syncthreads();
    if (t < 64) { atomicAdd(&Sagg[t], ls[t]); atomicAdd(&Sagg[64 + t], lq[t]); }
}

// out = relu(bn(t2,g3,b3) + x)
__global__ __launch_bounds__(256) void final_k(
    const float* __restrict__ t2, const float* __restrict__ x,
    const float* __restrict__ St2, const float* __restrict__ g3, const float* __restrict__ b3,
    float* __restrict__ out)
{
    __shared__ float scl[64], shl[64];
    const int t = threadIdx.x;
    if (t < 64) { float sc, sh; bn_coeff(St2, 64, t, g3, b3, 1.0f / (float)NN, sc, sh); scl[t] = sc; shl[t] = sh; }
    __syncthreads();
    int idx = blockIdx.x * 256 + t;          // float4 index; NN*64/4 = 640000 exactly
    int c0 = (idx & 15) * 4;
    const float4 a = *(const float4*)&t2[(size_t)idx * 4];
    const float4 b = *(const float4*)&x[(size_t)idx * 4];
    float4 o;
    o.x = fmaxf(fmaf(a.x, scl[c0 + 0], shl[c0 + 0]) + b.x, 0.f);
    o.y = fmaxf(fmaf(a.y, scl[c0 + 1], shl[c0 + 1]) + b.y, 0.f);
    o.z = fmaxf(fmaf(a.z, scl[c0 + 2], shl[c0 + 2]) + b.z, 0.f);
    o.w = fmaxf(fmaf(a.w, scl[c0 + 3], shl[c0 + 3]) + b.w, 0.f);
    *(float4*)&out[(size_t)idx * 4] = o;
}

extern "C" void kernel_launch(void* const* d_in, const int* in_sizes, int n_in,
                              void* d_out, int out_size, void* d_ws, size_t ws_size,
                              hipStream_t stream)
{
    const float* x    = (const float*)d_in[0];
    const float* pos  = (const float*)d_in[1];
    const int*   src  = (const int*)d_in[2];      // edge_index[0]; dst[e] == e>>4 by construction
    const float* W_in = (const float*)d_in[3];
    const float* g1   = (const float*)d_in[4];
    const float* b1   = (const float*)d_in[5];
    const float* W_v  = (const float*)d_in[6];
    const float* W_src= (const float*)d_in[7];
    const float* W_dst= (const float*)d_in[8];
    const float* Wp1  = (const float*)d_in[9];
    const float* bp1  = (const float*)d_in[10];
    const float* gp   = (const float*)d_in[11];
    const float* bp_  = (const float*)d_in[12];
    const float* Wp2  = (const float*)d_in[13];
    const float* bp2  = (const float*)d_in[14];
    const float* ga0  = (const float*)d_in[15];
    const float* ba0  = (const float*)d_in[16];
    const float* Wa1  = (const float*)d_in[17];
    const float* ba1  = (const float*)d_in[18];
    const float* ga1  = (const float*)d_in[19];
    const float* bb1  = (const float*)d_in[20];
    const float* Wa2  = (const float*)d_in[21];
    const float* ba2  = (const float*)d_in[22];
    const float* g2   = (const float*)d_in[23];
    const float* b2   = (const float*)d_in[24];
    const float* W_out= (const float*)d_in[25];
    const float* g3   = (const float*)d_in[26];
    const float* b3   = (const float*)d_in[27];
    float* out = (float*)d_out;

    float* wsf   = (float*)d_ws;
    float* S_t1  = wsf;          // 128
    float* S_q   = wsf + 128;    // 6 used
    float* S_a0  = wsf + 192;    // 128
    float* S_t   = wsf + 320;    // 16 used
    float* S_agg = wsf + 384;    // 128
    float* S_t2  = wsf + 512;    // 128
    const size_t N64 = (size_t)NN * 64;
    float* t1   = wsf + 1024;
    float* asrc = t1 + N64;
    float* adst = asrc + N64;
    float* vv   = adst + N64;
    float* q4   = vv + N64;            // [E] float4 (q0,q1,q2,src)
    float* tt   = q4 + 4 * (size_t)EE; // [E,8]
    float* agg  = t1;            // alias: t1 dead after gemm3
    float* t2   = asrc;          // alias: asrc dead after edge_t

    hipMemsetAsync(wsf, 0, 1024 * sizeof(float), stream);

    // t1 = x @ W_in (+stats)  ||  q4 = {q, src} (+stats3)   [independent, one launch]
    gemm0q_k<<<785, 256, 0, stream>>>(x, W_in, t1, S_t1, pos, src, Wp1, bp1, (float4*)q4, S_q);
    // h = relu(bn(t1)) staged once; {asrc,adst,vv} = h @ {W_src,W_dst,W_v}
    gemm3_k<<<625, 256, 0, stream>>>(t1, W_src, W_dst, W_v, asrc, adst, vv,
                                     S_t1, g1, b1, 1.0f / (float)NN);
    // raw stats of a0 (store-free) — wide-load node-per-wave
    edge_a0_k<<<2048, 256, 0, stream>>>((const float4*)q4, adst, asrc, Wp2, bp2, S_q, gp, bp_, S_a0);
    // t = relu(bn(a0)) @ Wa1 + ba1 (+stats8) — wave-private LDS-GEMM, barrier-free loop
    edge_t_k<<<2048, 256, 0, stream>>>((const float4*)q4, adst, asrc, Wp2, bp2, S_q, gp, bp_,
                                       S_a0, ga0, ba0, Wa1, ba1, tt, S_t);
    // a2,a3,softmax,agg (+stats) — wide-load, barrier-free loop
    edge_final_k<<<2500, 256, 0, stream>>>(tt, (const float4*)q4, vv, Wp2, bp2, S_q, gp, bp_,
                                           S_t, ga1, bb1, Wa2, ba2, agg, S_agg);
    // t2 = relu(bn(agg,g2,b2)) @ W_out (+stats)
    gemm1_k<<<625, 256, 0, stream>>>(agg, W_out, t2, S_agg, g2, b2, 1.0f / (float)NN, S_t2);
    // out = relu(bn(t2,g3,b3) + x)
    final_k<<<2500, 256, 0, stream>>>(t2, x, S_t2, g3, b3, out);
}